// Round 6
// baseline (2952.434 us; speedup 1.0000x reference)
//
#include <hip/hip_runtime.h>
#include <math.h>

#define NN   131072   // total inner nodes
#define GG   2048     // graphs
#define NPG  64       // nodes per graph
#define EE   1048576  // inner edges
#define EFN  32768    // outer edges
#define DD   128      // feature dim
#define KK   8        // sortpool k

// ---------------- utility ----------------
__global__ void fill_f32_kernel(float* __restrict__ p, float v, int nElems) {
  int i = blockIdx.x * 256 + threadIdx.x;
  if (i < nElems) p[i] = v;
}

__global__ void init_softmax_kernel(float* __restrict__ mx, float* __restrict__ sm, int nElems) {
  int i = blockIdx.x * 256 + threadIdx.x;
  if (i < nElems) { mx[i] = -INFINITY; sm[i] = 0.f; }
}

// x[i] = relu(token_emb[h[node]][d])
__global__ void embed_relu_kernel(const float* __restrict__ temb,
                                  const int* __restrict__ h,
                                  float* __restrict__ x, int total) {
  int i = blockIdx.x * 256 + threadIdx.x;
  if (i >= total) return;
  int node = i >> 7, d = i & 127;
  x[i] = fmaxf(temb[h[node] * DD + d], 0.f);
}

// ---------------- GEMM: out[M,128] = A[M,KD] @ W[KD,128] (+bias, relu) ----------------
// In-place safe when out == A (rows staged to LDS first; blocks own disjoint rows).
template <int KD, int ROWS>
__global__ __launch_bounds__(128) void gemm_kernel(
    const float* __restrict__ A, const float* __restrict__ W,
    const float* __restrict__ bias, float* __restrict__ out,
    int relu_flag) {
  __shared__ float As[ROWS * KD];
  const int row0 = blockIdx.x * ROWS;
  const int tid = threadIdx.x;  // output column
  for (int i = tid; i < ROWS * KD; i += 128) As[i] = A[(size_t)row0 * KD + i];
  __syncthreads();
  float acc[ROWS];
#pragma unroll
  for (int r = 0; r < ROWS; r++) acc[r] = 0.f;
  for (int k = 0; k < KD; k++) {
    float w = W[k * 128 + tid];
#pragma unroll
    for (int r = 0; r < ROWS; r++) acc[r] += As[r * KD + k] * w;
  }
  float b = bias ? bias[tid] : 0.f;
#pragma unroll
  for (int r = 0; r < ROWS; r++) {
    float v = acc[r] + b;
    if (relu_flag) v = fmaxf(v, 0.f);
    out[(size_t)(row0 + r) * 128 + tid] = v;
  }
}

// ---------------- attention logits: el[i]=f[i]·al, er[i]=f[i]·ar ----------------
__global__ __launch_bounds__(64) void attn_logits_kernel(
    const float* __restrict__ f, const float* __restrict__ al,
    const float* __restrict__ ar, float* __restrict__ el,
    float* __restrict__ er) {
  int node = blockIdx.x, lane = threadIdx.x;
  float v1 = f[(size_t)node * 128 + lane];
  float v2 = f[(size_t)node * 128 + 64 + lane];
  float sl = v1 * al[lane] + v2 * al[64 + lane];
  float sr = v1 * ar[lane] + v2 * ar[64 + lane];
#pragma unroll
  for (int off = 32; off; off >>= 1) {
    sl += __shfl_down(sl, off);
    sr += __shfl_down(sr, off);
  }
  if (lane == 0) { el[node] = sl; er[node] = sr; }
}

// ---------------- edge kernels (scores recomputed each pass, bit-identical) ----------------
static __device__ __forceinline__ void atomicMaxF(float* addr, float v) {
  int iv = __float_as_int(v);
  if (iv >= 0) atomicMax((int*)addr, iv);
  else atomicMin((unsigned int*)addr, (unsigned int)iv);
}

static __device__ __forceinline__ float edge_score(const float* el, const float* er,
                                                   int sv, int dv) {
  float v = el[sv] + er[dv];
  return v > 0.f ? v : 0.2f * v;  // leaky_relu(0.2)
}

__global__ void edge_max_kernel(const float* __restrict__ el,
                                const float* __restrict__ er,
                                const int* __restrict__ src,
                                const int* __restrict__ dst,
                                float* __restrict__ m, int nE) {
  int e = blockIdx.x * 256 + threadIdx.x;
  if (e >= nE) return;
  atomicMaxF(&m[dst[e]], edge_score(el, er, src[e], dst[e]));
}

__global__ void edge_expsum_kernel(const float* __restrict__ el,
                                   const float* __restrict__ er,
                                   const float* __restrict__ m,
                                   const int* __restrict__ src,
                                   const int* __restrict__ dst,
                                   float* __restrict__ s, int nE) {
  int e = blockIdx.x * 256 + threadIdx.x;
  if (e >= nE) return;
  int d = dst[e];
  atomicAdd(&s[d], expf(edge_score(el, er, src[e], d) - m[d]));
}

// one block (128 threads) per edge: out[dst] += alpha * f[src]
__global__ __launch_bounds__(128) void edge_aggregate_kernel(
    const float* __restrict__ f, const float* __restrict__ el,
    const float* __restrict__ er, const float* __restrict__ m,
    const float* __restrict__ s, const int* __restrict__ src,
    const int* __restrict__ dst, float* __restrict__ out, int nE) {
  int e = blockIdx.x;
  int d = threadIdx.x;
  int sv = src[e], dv = dst[e];
  float alpha = expf(edge_score(el, er, sv, dv) - m[dv]) / s[dv];
  atomicAdd(&out[(size_t)dv * 128 + d], alpha * f[(size_t)sv * 128 + d]);
}

__global__ void bias_relu_kernel(float* __restrict__ x,
                                 const float* __restrict__ b, int total) {
  int i = blockIdx.x * 256 + threadIdx.x;
  if (i >= total) return;
  x[i] = fmaxf(x[i] + b[i & 127], 0.f);
}

// key[i] = max over 128 features (== last element of ascending-sorted row)
__global__ __launch_bounds__(64) void row_max_kernel(const float* __restrict__ x,
                                                     float* __restrict__ key) {
  int node = blockIdx.x, lane = threadIdx.x;
  float v = fmaxf(x[(size_t)node * 128 + lane], x[(size_t)node * 128 + 64 + lane]);
#pragma unroll
  for (int off = 32; off; off >>= 1) v = fmaxf(v, __shfl_down(v, off));
  if (lane == 0) key[node] = v;
}

// SortPooling: rank nodes per graph by key (desc, stable tie-break = index,
// matching stable argsort of -key); top-8 rows get feature-sorted ascending
// and written to xp[g, rank*128 ..]
__global__ __launch_bounds__(64) void sort_pool_kernel(
    const float* __restrict__ x, const float* __restrict__ key,
    float* __restrict__ xp) {
  __shared__ float keys[NPG];
  int g = blockIdx.x, t = threadIdx.x;
  keys[t] = key[(size_t)g * NPG + t];
  __syncthreads();
  float myk = keys[t];
  int rank = 0;
  for (int j = 0; j < NPG; ++j) {
    float kj = keys[j];
    rank += (kj > myk) || (kj == myk && j < t);
  }
  if (rank < KK) {
    float vals[128];
    const float* row = x + (size_t)(g * NPG + t) * 128;
    for (int i = 0; i < 128; i++) vals[i] = row[i];
    for (int i = 1; i < 128; i++) {   // insertion sort ascending
      float v = vals[i];
      int j = i - 1;
      while (j >= 0 && vals[j] > v) { vals[j + 1] = vals[j]; --j; }
      vals[j + 1] = v;
    }
    float* o = xp + (size_t)g * (KK * 128) + rank * 128;
    for (int i = 0; i < 128; i++) o[i] = vals[i];
  }
}

// final classifier: out[g,2] = x[g]·Wc + bc   (fp32 out, per reference dtype)
__global__ __launch_bounds__(64) void classifier_kernel(
    const float* __restrict__ x, const float* __restrict__ Wc,
    const float* __restrict__ bc, float* __restrict__ out) {
  int g = blockIdx.x, lane = threadIdx.x;
  float v1 = x[(size_t)g * 128 + lane];
  float v2 = x[(size_t)g * 128 + 64 + lane];
  float a0 = v1 * Wc[lane * 2 + 0] + v2 * Wc[(64 + lane) * 2 + 0];
  float a1 = v1 * Wc[lane * 2 + 1] + v2 * Wc[(64 + lane) * 2 + 1];
#pragma unroll
  for (int off = 32; off; off >>= 1) {
    a0 += __shfl_down(a0, off);
    a1 += __shfl_down(a1, off);
  }
  if (lane == 0) {
    out[g * 2 + 0] = a0 + bc[0];
    out[g * 2 + 1] = a1 + bc[1];
  }
}

// ---------------- launcher ----------------
extern "C" void kernel_launch(void* const* d_in, const int* in_sizes, int n_in,
                              void* d_out, int out_size, void* d_ws, size_t ws_size,
                              hipStream_t stream) {
  // Required workspace: X (NN*DD) + F (NN*DD) + el/er/mx/sm (4*NN) floats.
  const size_t REQ_FLOATS = (size_t)NN * DD * 2 + (size_t)NN * 4;
  if (ws_size < REQ_FLOATS * sizeof(float)) {
    // all-zero signature (absmax would read 0.203125) => workspace too small
    hipMemsetAsync(d_out, 0, (size_t)out_size * sizeof(float), stream);
    return;
  }

  const int* h      = (const int*)d_in[0];
  const int* g_src  = (const int*)d_in[1];
  const int* g_dst  = (const int*)d_in[2];
  const int* fg_src = (const int*)d_in[3];
  const int* fg_dst = (const int*)d_in[4];
  const float* temb = (const float*)d_in[5];
  const float* W1 = (const float*)d_in[6];
  const float* al1 = (const float*)d_in[7];
  const float* ar1 = (const float*)d_in[8];
  const float* b1 = (const float*)d_in[9];
  const float* W2 = (const float*)d_in[10];
  const float* al2 = (const float*)d_in[11];
  const float* ar2 = (const float*)d_in[12];
  const float* b2 = (const float*)d_in[13];
  const float* W3 = (const float*)d_in[14];
  const float* al3 = (const float*)d_in[15];
  const float* ar3 = (const float*)d_in[16];
  const float* b3 = (const float*)d_in[17];
  const float* Wf = (const float*)d_in[18];
  const float* bfv = (const float*)d_in[19];
  const float* Wl = (const float*)d_in[20];
  const float* bl = (const float*)d_in[21];
  const float* Wl1 = (const float*)d_in[22];
  const float* bl1 = (const float*)d_in[23];
  const float* Wc = (const float*)d_in[24];
  const float* bc = (const float*)d_in[25];
  float* out = (float*)d_out;

  // ---- workspace layout (fp32) ----
  float* ws = (float*)d_ws;
  float* X  = ws;                          // NN*DD — features / agg target
  float* F  = X + (size_t)NN * DD;         // NN*DD — projected features
  float* el = F + (size_t)NN * DD;         // NN
  float* er = el + NN;                     // NN
  float* mx = er + NN;                     // NN
  float* sm = mx + NN;                     // NN
  // Carved from F once F is dead (after layer-2 aggregation):
  float* xp   = F;                          // GG*KK*DD = 2,097,152
  float* f3   = F + 2097152;                // GG*DD
  float* g3   = f3 + (size_t)GG * DD;       // GG*DD
  float* t1   = g3 + (size_t)GG * DD;       // GG*DD
  float* t2   = t1 + (size_t)GG * DD;       // GG*DD
  float* keyb = t2 + (size_t)GG * DD;       // NN

  const int totalND = NN * DD;

  // x = relu(token_emb[h])  -> X
  embed_relu_kernel<<<totalND / 256, 256, 0, stream>>>(temb, h, X, totalND);

  // inner GAT layer: F = X·W ; softmax-aggregate back into X (zeroed)
  auto gat_inner = [&](const float* W, const float* al, const float* ar, const float* bb) {
    gemm_kernel<DD, 8><<<NN / 8, 128, 0, stream>>>(X, W, nullptr, F, 0);
    attn_logits_kernel<<<NN, 64, 0, stream>>>(F, al, ar, el, er);
    init_softmax_kernel<<<(NN + 255) / 256, 256, 0, stream>>>(mx, sm, NN);
    fill_f32_kernel<<<totalND / 256, 256, 0, stream>>>(X, 0.f, totalND);
    edge_max_kernel<<<(EE + 255) / 256, 256, 0, stream>>>(el, er, g_src, g_dst, mx, EE);
    edge_expsum_kernel<<<(EE + 255) / 256, 256, 0, stream>>>(el, er, mx, g_src, g_dst, sm, EE);
    edge_aggregate_kernel<<<EE, 128, 0, stream>>>(F, el, er, mx, sm, g_src, g_dst, X, EE);
    bias_relu_kernel<<<totalND / 256, 256, 0, stream>>>(X, bb, totalND);
  };
  gat_inner(W1, al1, ar1, b1);
  gat_inner(W2, al2, ar2, b2);

  // linear_forward IN-PLACE: X = relu(X @ Wf + bf). F is dead from here on.
  gemm_kernel<DD, 8><<<NN / 8, 128, 0, stream>>>(X, Wf, bfv, X, 1);

  // sort pooling -> xp [G, 1024] (in F region)
  row_max_kernel<<<NN, 64, 0, stream>>>(X, keyb);
  sort_pool_kernel<<<GG, 64, 0, stream>>>(X, keyb, xp);

  // outer GAT: f3 = xp @ W3 ; softmax-aggregate over fg edges into g3
  gemm_kernel<KK * DD, 8><<<GG / 8, 128, 0, stream>>>(xp, W3, nullptr, f3, 0);
  attn_logits_kernel<<<GG, 64, 0, stream>>>(f3, al3, ar3, el, er);
  init_softmax_kernel<<<(GG + 255) / 256, 256, 0, stream>>>(mx, sm, GG);
  fill_f32_kernel<<<(GG * DD + 255) / 256, 256, 0, stream>>>(g3, 0.f, GG * DD);
  edge_max_kernel<<<(EFN + 255) / 256, 256, 0, stream>>>(el, er, fg_src, fg_dst, mx, EFN);
  edge_expsum_kernel<<<(EFN + 255) / 256, 256, 0, stream>>>(el, er, mx, fg_src, fg_dst, sm, EFN);
  edge_aggregate_kernel<<<EFN, 128, 0, stream>>>(f3, el, er, mx, sm, fg_src, fg_dst, g3, EFN);
  bias_relu_kernel<<<(GG * DD + 255) / 256, 256, 0, stream>>>(g3, b3, GG * DD);

  // t1 = relu(g3 @ Wl + bl); t2 = relu(t1 @ Wl1 + bl1)
  gemm_kernel<DD, 8><<<GG / 8, 128, 0, stream>>>(g3, Wl, bl, t1, 1);
  gemm_kernel<DD, 8><<<GG / 8, 128, 0, stream>>>(t1, Wl1, bl1, t2, 1);

  // classifier -> fp32 out [G,2]
  classifier_kernel<<<GG, 64, 0, stream>>>(t2, Wc, bc, out);
}

// Round 7
// 1826.503 us; speedup vs baseline: 1.6164x; 1.6164x over previous
//
#include <hip/hip_runtime.h>
#include <math.h>

#define NN   131072   // total inner nodes
#define GG   2048     // graphs
#define NPG  64       // nodes per graph
#define EE   1048576  // inner edges
#define EFN  32768    // outer edges
#define DD   128      // feature dim
#define KK   8        // sortpool k

// ---------------- utility ----------------
__global__ void fill_f32_kernel(float* __restrict__ p, float v, int nElems) {
  int i = blockIdx.x * 256 + threadIdx.x;
  if (i < nElems) p[i] = v;
}

__global__ void init_softmax_kernel(float* __restrict__ mx, float* __restrict__ sm, int nElems) {
  int i = blockIdx.x * 256 + threadIdx.x;
  if (i < nElems) { mx[i] = -INFINITY; sm[i] = 0.f; }
}

// x[i] = relu(token_emb[h[node]][d])
__global__ void embed_relu_kernel(const float* __restrict__ temb,
                                  const int* __restrict__ h,
                                  float* __restrict__ x, int total) {
  int i = blockIdx.x * 256 + threadIdx.x;
  if (i >= total) return;
  int node = i >> 7, d = i & 127;
  x[i] = fmaxf(temb[h[node] * DD + d], 0.f);
}

// ---------------- GEMM: out[M,128] = A[M,KD] @ W[KD,128] (+bias, relu) ----------------
// In-place safe when out == A (rows staged to LDS first; blocks own disjoint rows).
template <int KD, int ROWS>
__global__ __launch_bounds__(128) void gemm_kernel(
    const float* __restrict__ A, const float* __restrict__ W,
    const float* __restrict__ bias, float* __restrict__ out,
    int relu_flag) {
  __shared__ float As[ROWS * KD];
  const int row0 = blockIdx.x * ROWS;
  const int tid = threadIdx.x;  // output column
  for (int i = tid; i < ROWS * KD; i += 128) As[i] = A[(size_t)row0 * KD + i];
  __syncthreads();
  float acc[ROWS];
#pragma unroll
  for (int r = 0; r < ROWS; r++) acc[r] = 0.f;
  for (int k = 0; k < KD; k++) {
    float w = W[k * 128 + tid];
#pragma unroll
    for (int r = 0; r < ROWS; r++) acc[r] += As[r * KD + k] * w;
  }
  float b = bias ? bias[tid] : 0.f;
#pragma unroll
  for (int r = 0; r < ROWS; r++) {
    float v = acc[r] + b;
    if (relu_flag) v = fmaxf(v, 0.f);
    out[(size_t)(row0 + r) * 128 + tid] = v;
  }
}

// ---------------- attention logits: el[i]=f[i]·al, er[i]=f[i]·ar ----------------
__global__ __launch_bounds__(64) void attn_logits_kernel(
    const float* __restrict__ f, const float* __restrict__ al,
    const float* __restrict__ ar, float* __restrict__ el,
    float* __restrict__ er) {
  int node = blockIdx.x, lane = threadIdx.x;
  float v1 = f[(size_t)node * 128 + lane];
  float v2 = f[(size_t)node * 128 + 64 + lane];
  float sl = v1 * al[lane] + v2 * al[64 + lane];
  float sr = v1 * ar[lane] + v2 * ar[64 + lane];
#pragma unroll
  for (int off = 32; off; off >>= 1) {
    sl += __shfl_down(sl, off);
    sr += __shfl_down(sr, off);
  }
  if (lane == 0) { el[node] = sl; er[node] = sr; }
}

// ---------------- edge kernels (scores recomputed each pass, bit-identical) ----------------
static __device__ __forceinline__ void atomicMaxF(float* addr, float v) {
  int iv = __float_as_int(v);
  if (iv >= 0) atomicMax((int*)addr, iv);
  else atomicMin((unsigned int*)addr, (unsigned int)iv);
}

static __device__ __forceinline__ float edge_score(const float* el, const float* er,
                                                   int sv, int dv) {
  float v = el[sv] + er[dv];
  return v > 0.f ? v : 0.2f * v;  // leaky_relu(0.2)
}

__global__ void edge_max_kernel(const float* __restrict__ el,
                                const float* __restrict__ er,
                                const int* __restrict__ src,
                                const int* __restrict__ dst,
                                float* __restrict__ m, int nE) {
  int e = blockIdx.x * 256 + threadIdx.x;
  if (e >= nE) return;
  atomicMaxF(&m[dst[e]], edge_score(el, er, src[e], dst[e]));
}

__global__ void edge_expsum_kernel(const float* __restrict__ el,
                                   const float* __restrict__ er,
                                   const float* __restrict__ m,
                                   const int* __restrict__ src,
                                   const int* __restrict__ dst,
                                   float* __restrict__ s, int nE) {
  int e = blockIdx.x * 256 + threadIdx.x;
  if (e >= nE) return;
  int d = dst[e];
  atomicAdd(&s[d], expf(edge_score(el, er, src[e], d) - m[d]));
}

// one block (128 threads) per edge: out[dst] += alpha * f[src]
__global__ __launch_bounds__(128) void edge_aggregate_kernel(
    const float* __restrict__ f, const float* __restrict__ el,
    const float* __restrict__ er, const float* __restrict__ m,
    const float* __restrict__ s, const int* __restrict__ src,
    const int* __restrict__ dst, float* __restrict__ out, int nE) {
  int e = blockIdx.x;
  int d = threadIdx.x;
  int sv = src[e], dv = dst[e];
  float alpha = expf(edge_score(el, er, sv, dv) - m[dv]) / s[dv];
  atomicAdd(&out[(size_t)dv * 128 + d], alpha * f[(size_t)sv * 128 + d]);
}

__global__ void bias_relu_kernel(float* __restrict__ x,
                                 const float* __restrict__ b, int total) {
  int i = blockIdx.x * 256 + threadIdx.x;
  if (i >= total) return;
  x[i] = fmaxf(x[i] + b[i & 127], 0.f);
}

// key[i] = max over 128 features (== last element of ascending-sorted row)
__global__ __launch_bounds__(64) void row_max_kernel(const float* __restrict__ x,
                                                     float* __restrict__ key) {
  int node = blockIdx.x, lane = threadIdx.x;
  float v = fmaxf(x[(size_t)node * 128 + lane], x[(size_t)node * 128 + 64 + lane]);
#pragma unroll
  for (int off = 32; off; off >>= 1) v = fmaxf(v, __shfl_down(v, off));
  if (lane == 0) key[node] = v;
}

// SortPooling stage 1: rank nodes per graph by key (desc, stable tie-break =
// index, matching stable argsort of -key); write selected node index (within
// graph) for each of the top-8 ranks.
__global__ __launch_bounds__(64) void select_topk_kernel(
    const float* __restrict__ key, int* __restrict__ sel) {
  __shared__ float keys[NPG];
  int g = blockIdx.x, t = threadIdx.x;
  keys[t] = key[(size_t)g * NPG + t];
  __syncthreads();
  float myk = keys[t];
  int rank = 0;
  for (int j = 0; j < NPG; ++j) {
    float kj = keys[j];
    rank += (kj > myk) || (kj == myk && j < t);
  }
  if (rank < KK) sel[g * KK + rank] = t;
}

// SortPooling stage 2: one 128-thread block per selected row; LDS bitonic
// sort ascending (values only — equal values make stability moot), write to
// xp[g, rank*128 ..]. No scratch, no divergence.
__global__ __launch_bounds__(128) void sort_rows_kernel(
    const float* __restrict__ x, const int* __restrict__ sel,
    float* __restrict__ xp) {
  __shared__ float v[128];
  int b = blockIdx.x;            // 0 .. G*KK-1
  int t = threadIdx.x;
  int g = b >> 3, r = b & 7;
  int node = sel[b];
  v[t] = x[(size_t)(g * NPG + node) * 128 + t];
  __syncthreads();
  for (int k = 2; k <= 128; k <<= 1) {
    for (int j = k >> 1; j > 0; j >>= 1) {
      int ixj = t ^ j;
      if (ixj > t) {
        float a = v[t], bb = v[ixj];
        bool asc = ((t & k) == 0);
        if (asc ? (a > bb) : (a < bb)) { v[t] = bb; v[ixj] = a; }
      }
      __syncthreads();
    }
  }
  xp[(size_t)g * (KK * 128) + r * 128 + t] = v[t];
}

// final classifier: out[g,2] = x[g]·Wc + bc   (fp32 out, per reference dtype)
__global__ __launch_bounds__(64) void classifier_kernel(
    const float* __restrict__ x, const float* __restrict__ Wc,
    const float* __restrict__ bc, float* __restrict__ out) {
  int g = blockIdx.x, lane = threadIdx.x;
  float v1 = x[(size_t)g * 128 + lane];
  float v2 = x[(size_t)g * 128 + 64 + lane];
  float a0 = v1 * Wc[lane * 2 + 0] + v2 * Wc[(64 + lane) * 2 + 0];
  float a1 = v1 * Wc[lane * 2 + 1] + v2 * Wc[(64 + lane) * 2 + 1];
#pragma unroll
  for (int off = 32; off; off >>= 1) {
    a0 += __shfl_down(a0, off);
    a1 += __shfl_down(a1, off);
  }
  if (lane == 0) {
    out[g * 2 + 0] = a0 + bc[0];
    out[g * 2 + 1] = a1 + bc[1];
  }
}

// ---------------- launcher ----------------
extern "C" void kernel_launch(void* const* d_in, const int* in_sizes, int n_in,
                              void* d_out, int out_size, void* d_ws, size_t ws_size,
                              hipStream_t stream) {
  // Required workspace: X (NN*DD) + F (NN*DD) + el/er/mx/sm (4*NN) floats.
  const size_t REQ_FLOATS = (size_t)NN * DD * 2 + (size_t)NN * 4;
  if (ws_size < REQ_FLOATS * sizeof(float)) {
    hipMemsetAsync(d_out, 0, (size_t)out_size * sizeof(float), stream);
    return;
  }

  const int* h      = (const int*)d_in[0];
  const int* g_src  = (const int*)d_in[1];
  const int* g_dst  = (const int*)d_in[2];
  const int* fg_src = (const int*)d_in[3];
  const int* fg_dst = (const int*)d_in[4];
  const float* temb = (const float*)d_in[5];
  const float* W1 = (const float*)d_in[6];
  const float* al1 = (const float*)d_in[7];
  const float* ar1 = (const float*)d_in[8];
  const float* b1 = (const float*)d_in[9];
  const float* W2 = (const float*)d_in[10];
  const float* al2 = (const float*)d_in[11];
  const float* ar2 = (const float*)d_in[12];
  const float* b2 = (const float*)d_in[13];
  const float* W3 = (const float*)d_in[14];
  const float* al3 = (const float*)d_in[15];
  const float* ar3 = (const float*)d_in[16];
  const float* b3 = (const float*)d_in[17];
  const float* Wf = (const float*)d_in[18];
  const float* bfv = (const float*)d_in[19];
  const float* Wl = (const float*)d_in[20];
  const float* bl = (const float*)d_in[21];
  const float* Wl1 = (const float*)d_in[22];
  const float* bl1 = (const float*)d_in[23];
  const float* Wc = (const float*)d_in[24];
  const float* bc = (const float*)d_in[25];
  float* out = (float*)d_out;

  // ---- workspace layout (fp32) ----
  float* ws = (float*)d_ws;
  float* X  = ws;                          // NN*DD — features / agg target
  float* F  = X + (size_t)NN * DD;         // NN*DD — projected features
  float* el = F + (size_t)NN * DD;         // NN
  float* er = el + NN;                     // NN
  float* mx = er + NN;                     // NN
  float* sm = mx + NN;                     // NN
  // Carved from F once F is dead (after layer-2 aggregation):
  float* xp   = F;                          // GG*KK*DD = 2,097,152
  float* f3   = F + 2097152;                // GG*DD
  float* g3   = f3 + (size_t)GG * DD;       // GG*DD
  float* t1   = g3 + (size_t)GG * DD;       // GG*DD
  float* t2   = t1 + (size_t)GG * DD;       // GG*DD
  float* keyb = t2 + (size_t)GG * DD;       // NN
  int*   sel  = (int*)(keyb + NN);          // GG*KK ints

  const int totalND = NN * DD;

  // x = relu(token_emb[h])  -> X
  embed_relu_kernel<<<totalND / 256, 256, 0, stream>>>(temb, h, X, totalND);

  // inner GAT layer: F = X·W ; softmax-aggregate back into X (zeroed)
  auto gat_inner = [&](const float* W, const float* al, const float* ar, const float* bb) {
    gemm_kernel<DD, 8><<<NN / 8, 128, 0, stream>>>(X, W, nullptr, F, 0);
    attn_logits_kernel<<<NN, 64, 0, stream>>>(F, al, ar, el, er);
    init_softmax_kernel<<<(NN + 255) / 256, 256, 0, stream>>>(mx, sm, NN);
    fill_f32_kernel<<<totalND / 256, 256, 0, stream>>>(X, 0.f, totalND);
    edge_max_kernel<<<(EE + 255) / 256, 256, 0, stream>>>(el, er, g_src, g_dst, mx, EE);
    edge_expsum_kernel<<<(EE + 255) / 256, 256, 0, stream>>>(el, er, mx, g_src, g_dst, sm, EE);
    edge_aggregate_kernel<<<EE, 128, 0, stream>>>(F, el, er, mx, sm, g_src, g_dst, X, EE);
    bias_relu_kernel<<<totalND / 256, 256, 0, stream>>>(X, bb, totalND);
  };
  gat_inner(W1, al1, ar1, b1);
  gat_inner(W2, al2, ar2, b2);

  // linear_forward IN-PLACE: X = relu(X @ Wf + bf). F is dead from here on.
  gemm_kernel<DD, 8><<<NN / 8, 128, 0, stream>>>(X, Wf, bfv, X, 1);

  // sort pooling -> xp [G, 1024] (in F region)
  row_max_kernel<<<NN, 64, 0, stream>>>(X, keyb);
  select_topk_kernel<<<GG, 64, 0, stream>>>(keyb, sel);
  sort_rows_kernel<<<GG * KK, 128, 0, stream>>>(X, sel, xp);

  // outer GAT: f3 = xp @ W3 ; softmax-aggregate over fg edges into g3
  gemm_kernel<KK * DD, 8><<<GG / 8, 128, 0, stream>>>(xp, W3, nullptr, f3, 0);
  attn_logits_kernel<<<GG, 64, 0, stream>>>(f3, al3, ar3, el, er);
  init_softmax_kernel<<<(GG + 255) / 256, 256, 0, stream>>>(mx, sm, GG);
  fill_f32_kernel<<<(GG * DD + 255) / 256, 256, 0, stream>>>(g3, 0.f, GG * DD);
  edge_max_kernel<<<(EFN + 255) / 256, 256, 0, stream>>>(el, er, fg_src, fg_dst, mx, EFN);
  edge_expsum_kernel<<<(EFN + 255) / 256, 256, 0, stream>>>(el, er, mx, fg_src, fg_dst, sm, EFN);
  edge_aggregate_kernel<<<EFN, 128, 0, stream>>>(f3, el, er, mx, sm, fg_src, fg_dst, g3, EFN);
  bias_relu_kernel<<<(GG * DD + 255) / 256, 256, 0, stream>>>(g3, b3, GG * DD);

  // t1 = relu(g3 @ Wl + bl); t2 = relu(t1 @ Wl1 + bl1)
  gemm_kernel<DD, 8><<<GG / 8, 128, 0, stream>>>(g3, Wl, bl, t1, 1);
  gemm_kernel<DD, 8><<<GG / 8, 128, 0, stream>>>(t1, Wl1, bl1, t2, 1);

  // classifier -> fp32 out [G,2]
  classifier_kernel<<<GG, 64, 0, stream>>>(t2, Wc, bc, out);
}

// Round 8
// 1044.568 us; speedup vs baseline: 2.8265x; 1.7486x over previous
//
#include <hip/hip_runtime.h>
#include <math.h>

#define NN   131072   // total inner nodes
#define GG   2048     // graphs
#define NPG  64       // nodes per graph
#define EE   1048576  // inner edges
#define EFN  32768    // outer edges
#define DD   128      // feature dim
#define KK   8        // sortpool k

// ---------------- utility ----------------
__global__ void fill_f32_kernel(float* __restrict__ p, float v, int nElems) {
  int i = blockIdx.x * 256 + threadIdx.x;
  if (i < nElems) p[i] = v;
}

__global__ void zero_int_kernel(int* __restrict__ p, int nElems) {
  int i = blockIdx.x * 256 + threadIdx.x;
  if (i < nElems) p[i] = 0;
}

__global__ void init_softmax_kernel(float* __restrict__ mx, float* __restrict__ sm, int nElems) {
  int i = blockIdx.x * 256 + threadIdx.x;
  if (i < nElems) { mx[i] = -INFINITY; sm[i] = 0.f; }
}

// x[i] = relu(token_emb[h[node]][d])
__global__ void embed_relu_kernel(const float* __restrict__ temb,
                                  const int* __restrict__ h,
                                  float* __restrict__ x, int total) {
  int i = blockIdx.x * 256 + threadIdx.x;
  if (i >= total) return;
  int node = i >> 7, d = i & 127;
  x[i] = fmaxf(temb[h[node] * DD + d], 0.f);
}

// ---------------- GEMM: out[M,128] = A[M,KD] @ W[KD,128] (+bias, relu) ----------------
template <int KD, int ROWS>
__global__ __launch_bounds__(128) void gemm_kernel(
    const float* __restrict__ A, const float* __restrict__ W,
    const float* __restrict__ bias, float* __restrict__ out,
    int relu_flag) {
  __shared__ float As[ROWS * KD];
  const int row0 = blockIdx.x * ROWS;
  const int tid = threadIdx.x;
  for (int i = tid; i < ROWS * KD; i += 128) As[i] = A[(size_t)row0 * KD + i];
  __syncthreads();
  float acc[ROWS];
#pragma unroll
  for (int r = 0; r < ROWS; r++) acc[r] = 0.f;
  for (int k = 0; k < KD; k++) {
    float w = W[k * 128 + tid];
#pragma unroll
    for (int r = 0; r < ROWS; r++) acc[r] += As[r * KD + k] * w;
  }
  float b = bias ? bias[tid] : 0.f;
#pragma unroll
  for (int r = 0; r < ROWS; r++) {
    float v = acc[r] + b;
    if (relu_flag) v = fmaxf(v, 0.f);
    out[(size_t)(row0 + r) * 128 + tid] = v;
  }
}

// ---------------- attention logits ----------------
__global__ __launch_bounds__(64) void attn_logits_kernel(
    const float* __restrict__ f, const float* __restrict__ al,
    const float* __restrict__ ar, float* __restrict__ el,
    float* __restrict__ er) {
  int node = blockIdx.x, lane = threadIdx.x;
  float v1 = f[(size_t)node * 128 + lane];
  float v2 = f[(size_t)node * 128 + 64 + lane];
  float sl = v1 * al[lane] + v2 * al[64 + lane];
  float sr = v1 * ar[lane] + v2 * ar[64 + lane];
#pragma unroll
  for (int off = 32; off; off >>= 1) {
    sl += __shfl_down(sl, off);
    sr += __shfl_down(sr, off);
  }
  if (lane == 0) { el[node] = sl; er[node] = sr; }
}

// ---------------- CSR build ----------------
__global__ void hist_kernel(const int* __restrict__ dst, int* __restrict__ cnt, int nE) {
  int e = blockIdx.x * 256 + threadIdx.x;
  if (e < nE) atomicAdd(&cnt[dst[e]], 1);
}

// 1024 elems/block, 256 threads x 4; excl = in-block exclusive prefix, part[blk] = total
__global__ __launch_bounds__(256) void scan_block_kernel(
    const int* __restrict__ cnt, int* __restrict__ excl, int* __restrict__ part) {
  __shared__ int s[256];
  int blk = blockIdx.x, tid = threadIdx.x;
  int base = blk * 1024 + tid * 4;
  int a0 = cnt[base], a1 = cnt[base + 1], a2 = cnt[base + 2], a3 = cnt[base + 3];
  int tsum = a0 + a1 + a2 + a3;
  s[tid] = tsum; __syncthreads();
  for (int off = 1; off < 256; off <<= 1) {
    int v = (tid >= off) ? s[tid - off] : 0;
    __syncthreads();
    s[tid] += v;
    __syncthreads();
  }
  int texcl = s[tid] - tsum;
  excl[base]     = texcl;
  excl[base + 1] = texcl + a0;
  excl[base + 2] = texcl + a0 + a1;
  excl[base + 3] = texcl + a0 + a1 + a2;
  if (tid == 255) part[blk] = s[255];
}

__global__ __launch_bounds__(128) void scan_part_kernel(int* __restrict__ part) {
  __shared__ int s[128];
  int tid = threadIdx.x;
  int orig = part[tid];
  s[tid] = orig; __syncthreads();
  for (int off = 1; off < 128; off <<= 1) {
    int v = (tid >= off) ? s[tid - off] : 0;
    __syncthreads();
    s[tid] += v;
    __syncthreads();
  }
  part[tid] = s[tid] - orig;  // exclusive
}

__global__ void scan_add_kernel(int* __restrict__ row_ptr, const int* __restrict__ part,
                                int n, int total) {
  int i = blockIdx.x * 256 + threadIdx.x;
  if (i < n) row_ptr[i] += part[i >> 10];
  if (i == 0) row_ptr[n] = total;
}

__global__ void scatter_kernel(const int* __restrict__ dst, const int* __restrict__ row_ptr,
                               int* __restrict__ cursor, int* __restrict__ eidx, int nE) {
  int e = blockIdx.x * 256 + threadIdx.x;
  if (e >= nE) return;
  int d = dst[e];
  int pos = row_ptr[d] + atomicAdd(&cursor[d], 1);
  eidx[pos] = e;
}

// ---------------- fused CSR GAT aggregation ----------------
// One 128-thread block per dst node: in-block softmax (max, sum) over incoming
// edges, weighted accumulation of F[src] rows, fused bias+relu, single store.
__global__ __launch_bounds__(128) void gat_aggregate_csr_kernel(
    const float* __restrict__ F, const float* __restrict__ el,
    const float* __restrict__ er, const int* __restrict__ row_ptr,
    const int* __restrict__ eidx, const int* __restrict__ src,
    const float* __restrict__ bias, float* __restrict__ outX) {
  int d = blockIdx.x, tid = threadIdx.x;
  int beg = row_ptr[d], end = row_ptr[d + 1];
  int n = end - beg;
  float b = bias[tid];
  if (n == 0) { outX[(size_t)d * 128 + tid] = fmaxf(b, 0.f); return; }
  __shared__ float red[128];
  __shared__ float wts[128];
  __shared__ int   svs[128];
  float er_d = er[d];
  float acc = 0.f;
  if (n <= 128) {  // fast path (avg degree 8 — essentially always)
    float sc = -INFINITY; int sv = 0;
    if (tid < n) {
      sv = src[eidx[beg + tid]];
      float v = el[sv] + er_d;
      sc = v > 0.f ? v : 0.2f * v;
    }
    red[tid] = sc; __syncthreads();
    for (int off = 64; off; off >>= 1) {
      if (tid < off) red[tid] = fmaxf(red[tid], red[tid + off]);
      __syncthreads();
    }
    float m = red[0]; __syncthreads();
    float ex = (tid < n) ? expf(sc - m) : 0.f;
    red[tid] = ex; __syncthreads();
    for (int off = 64; off; off >>= 1) {
      if (tid < off) red[tid] += red[tid + off];
      __syncthreads();
    }
    float s = red[0]; __syncthreads();
    wts[tid] = ex / s;
    svs[tid] = sv;
    __syncthreads();
    for (int j = 0; j < n; ++j)
      acc += wts[j] * F[(size_t)svs[j] * 128 + tid];
  } else {  // general chunked path (degree > 128)
    float lm = -INFINITY;
    for (int t = tid; t < n; t += 128) {
      int sv = src[eidx[beg + t]];
      float v = el[sv] + er_d;
      v = v > 0.f ? v : 0.2f * v;
      lm = fmaxf(lm, v);
    }
    red[tid] = lm; __syncthreads();
    for (int off = 64; off; off >>= 1) {
      if (tid < off) red[tid] = fmaxf(red[tid], red[tid + off]);
      __syncthreads();
    }
    float m = red[0]; __syncthreads();
    float ls = 0.f;
    for (int t = tid; t < n; t += 128) {
      int sv = src[eidx[beg + t]];
      float v = el[sv] + er_d;
      v = v > 0.f ? v : 0.2f * v;
      ls += expf(v - m);
    }
    red[tid] = ls; __syncthreads();
    for (int off = 64; off; off >>= 1) {
      if (tid < off) red[tid] += red[tid + off];
      __syncthreads();
    }
    float s = red[0]; __syncthreads();
    for (int base = 0; base < n; base += 128) {
      int t = base + tid;
      if (t < n) {
        int sv = src[eidx[beg + t]];
        float v = el[sv] + er_d;
        v = v > 0.f ? v : 0.2f * v;
        wts[tid] = expf(v - m) / s;
        svs[tid] = sv;
      }
      __syncthreads();
      int cnt = min(128, n - base);
      for (int j = 0; j < cnt; ++j)
        acc += wts[j] * F[(size_t)svs[j] * 128 + tid];
      __syncthreads();
    }
  }
  outX[(size_t)d * 128 + tid] = fmaxf(acc + b, 0.f);
}

// ---------------- atomic-path edge kernels (outer graph + fallback) ----------------
static __device__ __forceinline__ void atomicMaxF(float* addr, float v) {
  int iv = __float_as_int(v);
  if (iv >= 0) atomicMax((int*)addr, iv);
  else atomicMin((unsigned int*)addr, (unsigned int)iv);
}

static __device__ __forceinline__ float edge_score(const float* el, const float* er,
                                                   int sv, int dv) {
  float v = el[sv] + er[dv];
  return v > 0.f ? v : 0.2f * v;
}

__global__ void edge_max_kernel(const float* __restrict__ el,
                                const float* __restrict__ er,
                                const int* __restrict__ src,
                                const int* __restrict__ dst,
                                float* __restrict__ m, int nE) {
  int e = blockIdx.x * 256 + threadIdx.x;
  if (e >= nE) return;
  atomicMaxF(&m[dst[e]], edge_score(el, er, src[e], dst[e]));
}

__global__ void edge_expsum_kernel(const float* __restrict__ el,
                                   const float* __restrict__ er,
                                   const float* __restrict__ m,
                                   const int* __restrict__ src,
                                   const int* __restrict__ dst,
                                   float* __restrict__ s, int nE) {
  int e = blockIdx.x * 256 + threadIdx.x;
  if (e >= nE) return;
  int d = dst[e];
  atomicAdd(&s[d], expf(edge_score(el, er, src[e], d) - m[d]));
}

__global__ __launch_bounds__(128) void edge_aggregate_kernel(
    const float* __restrict__ f, const float* __restrict__ el,
    const float* __restrict__ er, const float* __restrict__ m,
    const float* __restrict__ s, const int* __restrict__ src,
    const int* __restrict__ dst, float* __restrict__ out, int nE) {
  int e = blockIdx.x;
  int d = threadIdx.x;
  int sv = src[e], dv = dst[e];
  float alpha = expf(edge_score(el, er, sv, dv) - m[dv]) / s[dv];
  atomicAdd(&out[(size_t)dv * 128 + d], alpha * f[(size_t)sv * 128 + d]);
}

__global__ void bias_relu_kernel(float* __restrict__ x,
                                 const float* __restrict__ b, int total) {
  int i = blockIdx.x * 256 + threadIdx.x;
  if (i >= total) return;
  x[i] = fmaxf(x[i] + b[i & 127], 0.f);
}

// ---------------- sort pooling ----------------
__global__ __launch_bounds__(64) void row_max_kernel(const float* __restrict__ x,
                                                     float* __restrict__ key) {
  int node = blockIdx.x, lane = threadIdx.x;
  float v = fmaxf(x[(size_t)node * 128 + lane], x[(size_t)node * 128 + 64 + lane]);
#pragma unroll
  for (int off = 32; off; off >>= 1) v = fmaxf(v, __shfl_down(v, off));
  if (lane == 0) key[node] = v;
}

__global__ __launch_bounds__(64) void select_topk_kernel(
    const float* __restrict__ key, int* __restrict__ sel) {
  __shared__ float keys[NPG];
  int g = blockIdx.x, t = threadIdx.x;
  keys[t] = key[(size_t)g * NPG + t];
  __syncthreads();
  float myk = keys[t];
  int rank = 0;
  for (int j = 0; j < NPG; ++j) {
    float kj = keys[j];
    rank += (kj > myk) || (kj == myk && j < t);
  }
  if (rank < KK) sel[g * KK + rank] = t;
}

__global__ __launch_bounds__(128) void sort_rows_kernel(
    const float* __restrict__ x, const int* __restrict__ sel,
    float* __restrict__ xp) {
  __shared__ float v[128];
  int b = blockIdx.x;
  int t = threadIdx.x;
  int g = b >> 3, r = b & 7;
  int node = sel[b];
  v[t] = x[(size_t)(g * NPG + node) * 128 + t];
  __syncthreads();
  for (int k = 2; k <= 128; k <<= 1) {
    for (int j = k >> 1; j > 0; j >>= 1) {
      int ixj = t ^ j;
      if (ixj > t) {
        float a = v[t], bb = v[ixj];
        bool asc = ((t & k) == 0);
        if (asc ? (a > bb) : (a < bb)) { v[t] = bb; v[ixj] = a; }
      }
      __syncthreads();
    }
  }
  xp[(size_t)g * (KK * 128) + r * 128 + t] = v[t];
}

// ---------------- classifier ----------------
__global__ __launch_bounds__(64) void classifier_kernel(
    const float* __restrict__ x, const float* __restrict__ Wc,
    const float* __restrict__ bc, float* __restrict__ out) {
  int g = blockIdx.x, lane = threadIdx.x;
  float v1 = x[(size_t)g * 128 + lane];
  float v2 = x[(size_t)g * 128 + 64 + lane];
  float a0 = v1 * Wc[lane * 2 + 0] + v2 * Wc[(64 + lane) * 2 + 0];
  float a1 = v1 * Wc[lane * 2 + 1] + v2 * Wc[(64 + lane) * 2 + 1];
#pragma unroll
  for (int off = 32; off; off >>= 1) {
    a0 += __shfl_down(a0, off);
    a1 += __shfl_down(a1, off);
  }
  if (lane == 0) {
    out[g * 2 + 0] = a0 + bc[0];
    out[g * 2 + 1] = a1 + bc[1];
  }
}

// ---------------- launcher ----------------
extern "C" void kernel_launch(void* const* d_in, const int* in_sizes, int n_in,
                              void* d_out, int out_size, void* d_ws, size_t ws_size,
                              hipStream_t stream) {
  const size_t BASE_FLOATS = (size_t)NN * DD * 2 + (size_t)NN * 4;  // X,F,el,er,mx,sm
  const size_t CSR_INTS = (size_t)(NN + 1) + NN + EE + 128;          // row_ptr,cursor,eidx,part
  if (ws_size < BASE_FLOATS * sizeof(float)) {
    hipMemsetAsync(d_out, 0, (size_t)out_size * sizeof(float), stream);
    return;
  }
  const bool use_csr = ws_size >= BASE_FLOATS * sizeof(float) + CSR_INTS * sizeof(int);

  const int* h      = (const int*)d_in[0];
  const int* g_src  = (const int*)d_in[1];
  const int* g_dst  = (const int*)d_in[2];
  const int* fg_src = (const int*)d_in[3];
  const int* fg_dst = (const int*)d_in[4];
  const float* temb = (const float*)d_in[5];
  const float* W1 = (const float*)d_in[6];
  const float* al1 = (const float*)d_in[7];
  const float* ar1 = (const float*)d_in[8];
  const float* b1 = (const float*)d_in[9];
  const float* W2 = (const float*)d_in[10];
  const float* al2 = (const float*)d_in[11];
  const float* ar2 = (const float*)d_in[12];
  const float* b2 = (const float*)d_in[13];
  const float* W3 = (const float*)d_in[14];
  const float* al3 = (const float*)d_in[15];
  const float* ar3 = (const float*)d_in[16];
  const float* b3 = (const float*)d_in[17];
  const float* Wf = (const float*)d_in[18];
  const float* bfv = (const float*)d_in[19];
  const float* Wl = (const float*)d_in[20];
  const float* bl = (const float*)d_in[21];
  const float* Wl1 = (const float*)d_in[22];
  const float* bl1 = (const float*)d_in[23];
  const float* Wc = (const float*)d_in[24];
  const float* bc = (const float*)d_in[25];
  float* out = (float*)d_out;

  // ---- workspace layout ----
  float* ws = (float*)d_ws;
  float* X  = ws;
  float* F  = X + (size_t)NN * DD;
  float* el = F + (size_t)NN * DD;
  float* er = el + NN;
  float* mx = er + NN;
  float* sm = mx + NN;
  // int region after floats (CSR path only)
  int* row_ptr = (int*)(sm + NN);          // NN+1
  int* cursor  = row_ptr + NN + 1;         // NN
  int* eidx    = cursor + NN;              // EE
  int* part    = eidx + EE;                // 128
  // carved from F once F is dead (after layer-2 aggregation):
  float* xp   = F;                          // GG*KK*DD
  float* f3   = F + 2097152;
  float* g3   = f3 + (size_t)GG * DD;
  float* t1   = g3 + (size_t)GG * DD;
  float* t2   = t1 + (size_t)GG * DD;
  float* keyb = t2 + (size_t)GG * DD;       // NN
  int*   sel  = (int*)(keyb + NN);          // GG*KK

  const int totalND = NN * DD;

  if (use_csr) {
    // ---- build CSR of inner graph by dst (reused by both GAT layers) ----
    zero_int_kernel<<<NN / 256, 256, 0, stream>>>(cursor, NN);
    hist_kernel<<<EE / 256, 256, 0, stream>>>(g_dst, cursor, EE);
    scan_block_kernel<<<NN / 1024, 256, 0, stream>>>(cursor, row_ptr, part);
    scan_part_kernel<<<1, 128, 0, stream>>>(part);
    scan_add_kernel<<<(NN + 255) / 256, 256, 0, stream>>>(row_ptr, part, NN, EE);
    zero_int_kernel<<<NN / 256, 256, 0, stream>>>(cursor, NN);
    scatter_kernel<<<EE / 256, 256, 0, stream>>>(g_dst, row_ptr, cursor, eidx, EE);
  }

  // x = relu(token_emb[h]) -> X
  embed_relu_kernel<<<totalND / 256, 256, 0, stream>>>(temb, h, X, totalND);

  // inner GAT layer
  auto gat_inner = [&](const float* W, const float* al, const float* ar, const float* bb) {
    gemm_kernel<DD, 8><<<NN / 8, 128, 0, stream>>>(X, W, nullptr, F, 0);
    attn_logits_kernel<<<NN, 64, 0, stream>>>(F, al, ar, el, er);
    if (use_csr) {
      gat_aggregate_csr_kernel<<<NN, 128, 0, stream>>>(F, el, er, row_ptr, eidx, g_src, bb, X);
    } else {
      init_softmax_kernel<<<(NN + 255) / 256, 256, 0, stream>>>(mx, sm, NN);
      fill_f32_kernel<<<totalND / 256, 256, 0, stream>>>(X, 0.f, totalND);
      edge_max_kernel<<<(EE + 255) / 256, 256, 0, stream>>>(el, er, g_src, g_dst, mx, EE);
      edge_expsum_kernel<<<(EE + 255) / 256, 256, 0, stream>>>(el, er, mx, g_src, g_dst, sm, EE);
      edge_aggregate_kernel<<<EE, 128, 0, stream>>>(F, el, er, mx, sm, g_src, g_dst, X, EE);
      bias_relu_kernel<<<totalND / 256, 256, 0, stream>>>(X, bb, totalND);
    }
  };
  gat_inner(W1, al1, ar1, b1);
  gat_inner(W2, al2, ar2, b2);

  // linear_forward IN-PLACE: X = relu(X @ Wf + bf). F dead after this point.
  gemm_kernel<DD, 8><<<NN / 8, 128, 0, stream>>>(X, Wf, bfv, X, 1);

  // sort pooling -> xp [G, 1024]
  row_max_kernel<<<NN, 64, 0, stream>>>(X, keyb);
  select_topk_kernel<<<GG, 64, 0, stream>>>(keyb, sel);
  sort_rows_kernel<<<GG * KK, 128, 0, stream>>>(X, sel, xp);

  // outer GAT over fg (atomic path — small)
  gemm_kernel<KK * DD, 8><<<GG / 8, 128, 0, stream>>>(xp, W3, nullptr, f3, 0);
  attn_logits_kernel<<<GG, 64, 0, stream>>>(f3, al3, ar3, el, er);
  init_softmax_kernel<<<(GG + 255) / 256, 256, 0, stream>>>(mx, sm, GG);
  fill_f32_kernel<<<(GG * DD + 255) / 256, 256, 0, stream>>>(g3, 0.f, GG * DD);
  edge_max_kernel<<<(EFN + 255) / 256, 256, 0, stream>>>(el, er, fg_src, fg_dst, mx, EFN);
  edge_expsum_kernel<<<(EFN + 255) / 256, 256, 0, stream>>>(el, er, mx, fg_src, fg_dst, sm, EFN);
  edge_aggregate_kernel<<<EFN, 128, 0, stream>>>(f3, el, er, mx, sm, fg_src, fg_dst, g3, EFN);
  bias_relu_kernel<<<(GG * DD + 255) / 256, 256, 0, stream>>>(g3, b3, GG * DD);

  // t1 = relu(g3 @ Wl + bl); t2 = relu(t1 @ Wl1 + bl1)
  gemm_kernel<DD, 8><<<GG / 8, 128, 0, stream>>>(g3, Wl, bl, t1, 1);
  gemm_kernel<DD, 8><<<GG / 8, 128, 0, stream>>>(t1, Wl1, bl1, t2, 1);

  // classifier -> fp32 out [G,2]
  classifier_kernel<<<GG, 64, 0, stream>>>(t2, Wc, bc, out);
}

// Round 9
// 880.292 us; speedup vs baseline: 3.3539x; 1.1866x over previous
//
#include <hip/hip_runtime.h>
#include <math.h>

#define NN   131072   // total inner nodes
#define GG   2048     // graphs
#define NPG  64       // nodes per graph
#define EE   1048576  // inner edges
#define EFN  32768    // outer edges
#define DD   128      // feature dim
#define KK   8        // sortpool k

// ---------------- utility ----------------
__global__ void fill_f32_kernel(float* __restrict__ p, float v, int nElems) {
  int i = blockIdx.x * 256 + threadIdx.x;
  if (i < nElems) p[i] = v;
}

__global__ void zero_int_kernel(int* __restrict__ p, int nElems) {
  int i = blockIdx.x * 256 + threadIdx.x;
  if (i < nElems) p[i] = 0;
}

__global__ void init_softmax_kernel(float* __restrict__ mx, float* __restrict__ sm, int nElems) {
  int i = blockIdx.x * 256 + threadIdx.x;
  if (i < nElems) { mx[i] = -INFINITY; sm[i] = 0.f; }
}

// x[i] = relu(token_emb[h[node]][d])   (fallback path only)
__global__ void embed_relu_kernel(const float* __restrict__ temb,
                                  const int* __restrict__ h,
                                  float* __restrict__ x, int total) {
  int i = blockIdx.x * 256 + threadIdx.x;
  if (i >= total) return;
  int node = i >> 7, d = i & 127;
  x[i] = fmaxf(temb[h[node] * DD + d], 0.f);
}

// ---------------- small / generic GEMM (outer graph, fallback) ----------------
template <int KD, int ROWS>
__global__ __launch_bounds__(128) void gemm_kernel(
    const float* __restrict__ A, const float* __restrict__ W,
    const float* __restrict__ bias, float* __restrict__ out,
    int relu_flag) {
  __shared__ float As[ROWS * KD];
  const int row0 = blockIdx.x * ROWS;
  const int tid = threadIdx.x;
  for (int i = tid; i < ROWS * KD; i += 128) As[i] = A[(size_t)row0 * KD + i];
  __syncthreads();
  float acc[ROWS];
#pragma unroll
  for (int r = 0; r < ROWS; r++) acc[r] = 0.f;
  for (int k = 0; k < KD; k++) {
    float w = W[k * 128 + tid];
#pragma unroll
    for (int r = 0; r < ROWS; r++) acc[r] += As[r * KD + k] * w;
  }
  float b = bias ? bias[tid] : 0.f;
#pragma unroll
  for (int r = 0; r < ROWS; r++) {
    float v = acc[r] + b;
    if (relu_flag) v = fmaxf(v, 0.f);
    out[(size_t)(row0 + r) * 128 + tid] = v;
  }
}

// ---------------- fused tiled GEMM: out[M,128] = act(A)[M,128] @ W[128,128] ----------------
// 64 rows/block, 256 threads; thread (rg=t>>5, cg=t&31) computes 8 rows x 4 cols.
// SRC_MODE 0: A from global. SRC_MODE 1: A = relu(temb[h[row]]) gathered at staging.
// EPI 0: plain store. EPI 1: store + el/er = row-dot(al/ar) via shuffle reduce.
// EPI 2: relu(acc+bias) store (in-place safe) + row max -> keyb.
template <int SRC_MODE, int EPI>
__global__ __launch_bounds__(256) void gemm128_fused(
    const float* __restrict__ A, const float* __restrict__ temb,
    const int* __restrict__ hidx, const float* __restrict__ W,
    const float* __restrict__ bias, float* __restrict__ out,
    const float* __restrict__ al, const float* __restrict__ ar,
    float* __restrict__ el, float* __restrict__ er,
    float* __restrict__ keyb) {
  __shared__ float As[64 * 128];
  const int t = threadIdx.x;
  const int row0 = blockIdx.x * 64;
  // stage 64x128 tile (float4)
  for (int idx = t; idx < 64 * 32; idx += 256) {
    int r = idx >> 5, c4 = (idx & 31) << 2;
    if (SRC_MODE == 1) {
      const float* src = temb + (size_t)hidx[row0 + r] * 128 + c4;
      float4 v = *(const float4*)src;
      v.x = fmaxf(v.x, 0.f); v.y = fmaxf(v.y, 0.f);
      v.z = fmaxf(v.z, 0.f); v.w = fmaxf(v.w, 0.f);
      *(float4*)&As[r * 128 + c4] = v;
    } else {
      *(float4*)&As[r * 128 + c4] = *(const float4*)(A + (size_t)(row0 + r) * 128 + c4);
    }
  }
  __syncthreads();
  const int rg = t >> 5, cg = t & 31;
  const int r0 = rg * 8, c0 = cg * 4;
  float acc[8][4];
#pragma unroll
  for (int i = 0; i < 8; i++)
#pragma unroll
    for (int j = 0; j < 4; j++) acc[i][j] = 0.f;
  for (int k = 0; k < 128; k += 4) {
    float4 w0 = *(const float4*)(W + (size_t)(k + 0) * 128 + c0);
    float4 w1 = *(const float4*)(W + (size_t)(k + 1) * 128 + c0);
    float4 w2 = *(const float4*)(W + (size_t)(k + 2) * 128 + c0);
    float4 w3 = *(const float4*)(W + (size_t)(k + 3) * 128 + c0);
#pragma unroll
    for (int i = 0; i < 8; i++) {
      float4 a = *(const float4*)&As[(r0 + i) * 128 + k];
      acc[i][0] += a.x * w0.x + a.y * w1.x + a.z * w2.x + a.w * w3.x;
      acc[i][1] += a.x * w0.y + a.y * w1.y + a.z * w2.y + a.w * w3.y;
      acc[i][2] += a.x * w0.z + a.y * w1.z + a.z * w2.z + a.w * w3.z;
      acc[i][3] += a.x * w0.w + a.y * w1.w + a.z * w2.w + a.w * w3.w;
    }
  }
  if (EPI == 0) {
#pragma unroll
    for (int i = 0; i < 8; i++) {
      float4 v = make_float4(acc[i][0], acc[i][1], acc[i][2], acc[i][3]);
      *(float4*)(out + (size_t)(row0 + r0 + i) * 128 + c0) = v;
    }
  } else if (EPI == 1) {
    float4 alv = *(const float4*)(al + c0);
    float4 arv = *(const float4*)(ar + c0);
#pragma unroll
    for (int i = 0; i < 8; i++) {
      float4 v = make_float4(acc[i][0], acc[i][1], acc[i][2], acc[i][3]);
      *(float4*)(out + (size_t)(row0 + r0 + i) * 128 + c0) = v;
      float pl = v.x * alv.x + v.y * alv.y + v.z * alv.z + v.w * alv.w;
      float pr = v.x * arv.x + v.y * arv.y + v.z * arv.z + v.w * arv.w;
#pragma unroll
      for (int off = 16; off; off >>= 1) {
        pl += __shfl_down(pl, off, 32);
        pr += __shfl_down(pr, off, 32);
      }
      if (cg == 0) {
        el[row0 + r0 + i] = pl;
        er[row0 + r0 + i] = pr;
      }
    }
  } else {  // EPI == 2
    float4 bv = *(const float4*)(bias + c0);
#pragma unroll
    for (int i = 0; i < 8; i++) {
      float4 v;
      v.x = fmaxf(acc[i][0] + bv.x, 0.f);
      v.y = fmaxf(acc[i][1] + bv.y, 0.f);
      v.z = fmaxf(acc[i][2] + bv.z, 0.f);
      v.w = fmaxf(acc[i][3] + bv.w, 0.f);
      *(float4*)(out + (size_t)(row0 + r0 + i) * 128 + c0) = v;
      float pm = fmaxf(fmaxf(v.x, v.y), fmaxf(v.z, v.w));
#pragma unroll
      for (int off = 16; off; off >>= 1) pm = fmaxf(pm, __shfl_down(pm, off, 32));
      if (cg == 0) keyb[row0 + r0 + i] = pm;
    }
  }
}

// ---------------- attention logits (outer graph, fallback) ----------------
__global__ __launch_bounds__(64) void attn_logits_kernel(
    const float* __restrict__ f, const float* __restrict__ al,
    const float* __restrict__ ar, float* __restrict__ el,
    float* __restrict__ er) {
  int node = blockIdx.x, lane = threadIdx.x;
  float v1 = f[(size_t)node * 128 + lane];
  float v2 = f[(size_t)node * 128 + 64 + lane];
  float sl = v1 * al[lane] + v2 * al[64 + lane];
  float sr = v1 * ar[lane] + v2 * ar[64 + lane];
#pragma unroll
  for (int off = 32; off; off >>= 1) {
    sl += __shfl_down(sl, off);
    sr += __shfl_down(sr, off);
  }
  if (lane == 0) { el[node] = sl; er[node] = sr; }
}

// ---------------- CSR build ----------------
__global__ void hist_kernel(const int* __restrict__ dst, int* __restrict__ cnt, int nE) {
  int e = blockIdx.x * 256 + threadIdx.x;
  if (e < nE) atomicAdd(&cnt[dst[e]], 1);
}

__global__ __launch_bounds__(256) void scan_block_kernel(
    const int* __restrict__ cnt, int* __restrict__ excl, int* __restrict__ part) {
  __shared__ int s[256];
  int blk = blockIdx.x, tid = threadIdx.x;
  int base = blk * 1024 + tid * 4;
  int a0 = cnt[base], a1 = cnt[base + 1], a2 = cnt[base + 2], a3 = cnt[base + 3];
  int tsum = a0 + a1 + a2 + a3;
  s[tid] = tsum; __syncthreads();
  for (int off = 1; off < 256; off <<= 1) {
    int v = (tid >= off) ? s[tid - off] : 0;
    __syncthreads();
    s[tid] += v;
    __syncthreads();
  }
  int texcl = s[tid] - tsum;
  excl[base]     = texcl;
  excl[base + 1] = texcl + a0;
  excl[base + 2] = texcl + a0 + a1;
  excl[base + 3] = texcl + a0 + a1 + a2;
  if (tid == 255) part[blk] = s[255];
}

__global__ __launch_bounds__(128) void scan_part_kernel(int* __restrict__ part) {
  __shared__ int s[128];
  int tid = threadIdx.x;
  int orig = part[tid];
  s[tid] = orig; __syncthreads();
  for (int off = 1; off < 128; off <<= 1) {
    int v = (tid >= off) ? s[tid - off] : 0;
    __syncthreads();
    s[tid] += v;
    __syncthreads();
  }
  part[tid] = s[tid] - orig;
}

__global__ void scan_add_kernel(int* __restrict__ row_ptr, const int* __restrict__ part,
                                int n, int total) {
  int i = blockIdx.x * 256 + threadIdx.x;
  if (i < n) row_ptr[i] += part[i >> 10];
  if (i == 0) row_ptr[n] = total;
}

__global__ void scatter_kernel(const int* __restrict__ dst, const int* __restrict__ row_ptr,
                               int* __restrict__ cursor, int* __restrict__ eidx, int nE) {
  int e = blockIdx.x * 256 + threadIdx.x;
  if (e >= nE) return;
  int d = dst[e];
  int pos = row_ptr[d] + atomicAdd(&cursor[d], 1);
  eidx[pos] = e;
}

// ---------------- fused CSR GAT aggregation ----------------
__global__ __launch_bounds__(128) void gat_aggregate_csr_kernel(
    const float* __restrict__ F, const float* __restrict__ el,
    const float* __restrict__ er, const int* __restrict__ row_ptr,
    const int* __restrict__ eidx, const int* __restrict__ src,
    const float* __restrict__ bias, float* __restrict__ outX) {
  int d = blockIdx.x, tid = threadIdx.x;
  int beg = row_ptr[d], end = row_ptr[d + 1];
  int n = end - beg;
  float b = bias[tid];
  if (n == 0) { outX[(size_t)d * 128 + tid] = fmaxf(b, 0.f); return; }
  __shared__ float red[128];
  __shared__ float wts[128];
  __shared__ int   svs[128];
  float er_d = er[d];
  float acc = 0.f;
  if (n <= 128) {
    float sc = -INFINITY; int sv = 0;
    if (tid < n) {
      sv = src[eidx[beg + tid]];
      float v = el[sv] + er_d;
      sc = v > 0.f ? v : 0.2f * v;
    }
    red[tid] = sc; __syncthreads();
    for (int off = 64; off; off >>= 1) {
      if (tid < off) red[tid] = fmaxf(red[tid], red[tid + off]);
      __syncthreads();
    }
    float m = red[0]; __syncthreads();
    float ex = (tid < n) ? expf(sc - m) : 0.f;
    red[tid] = ex; __syncthreads();
    for (int off = 64; off; off >>= 1) {
      if (tid < off) red[tid] += red[tid + off];
      __syncthreads();
    }
    float s = red[0]; __syncthreads();
    wts[tid] = ex / s;
    svs[tid] = sv;
    __syncthreads();
    for (int j = 0; j < n; ++j)
      acc += wts[j] * F[(size_t)svs[j] * 128 + tid];
  } else {
    float lm = -INFINITY;
    for (int t = tid; t < n; t += 128) {
      int sv = src[eidx[beg + t]];
      float v = el[sv] + er_d;
      v = v > 0.f ? v : 0.2f * v;
      lm = fmaxf(lm, v);
    }
    red[tid] = lm; __syncthreads();
    for (int off = 64; off; off >>= 1) {
      if (tid < off) red[tid] = fmaxf(red[tid], red[tid + off]);
      __syncthreads();
    }
    float m = red[0]; __syncthreads();
    float ls = 0.f;
    for (int t = tid; t < n; t += 128) {
      int sv = src[eidx[beg + t]];
      float v = el[sv] + er_d;
      v = v > 0.f ? v : 0.2f * v;
      ls += expf(v - m);
    }
    red[tid] = ls; __syncthreads();
    for (int off = 64; off; off >>= 1) {
      if (tid < off) red[tid] += red[tid + off];
      __syncthreads();
    }
    float s = red[0]; __syncthreads();
    for (int base = 0; base < n; base += 128) {
      int t = base + tid;
      if (t < n) {
        int sv = src[eidx[beg + t]];
        float v = el[sv] + er_d;
        v = v > 0.f ? v : 0.2f * v;
        wts[tid] = expf(v - m) / s;
        svs[tid] = sv;
      }
      __syncthreads();
      int cnt = min(128, n - base);
      for (int j = 0; j < cnt; ++j)
        acc += wts[j] * F[(size_t)svs[j] * 128 + tid];
      __syncthreads();
    }
  }
  outX[(size_t)d * 128 + tid] = fmaxf(acc + b, 0.f);
}

// ---------------- atomic-path edge kernels (outer graph + fallback) ----------------
static __device__ __forceinline__ void atomicMaxF(float* addr, float v) {
  int iv = __float_as_int(v);
  if (iv >= 0) atomicMax((int*)addr, iv);
  else atomicMin((unsigned int*)addr, (unsigned int)iv);
}

static __device__ __forceinline__ float edge_score(const float* el, const float* er,
                                                   int sv, int dv) {
  float v = el[sv] + er[dv];
  return v > 0.f ? v : 0.2f * v;
}

__global__ void edge_max_kernel(const float* __restrict__ el,
                                const float* __restrict__ er,
                                const int* __restrict__ src,
                                const int* __restrict__ dst,
                                float* __restrict__ m, int nE) {
  int e = blockIdx.x * 256 + threadIdx.x;
  if (e >= nE) return;
  atomicMaxF(&m[dst[e]], edge_score(el, er, src[e], dst[e]));
}

__global__ void edge_expsum_kernel(const float* __restrict__ el,
                                   const float* __restrict__ er,
                                   const float* __restrict__ m,
                                   const int* __restrict__ src,
                                   const int* __restrict__ dst,
                                   float* __restrict__ s, int nE) {
  int e = blockIdx.x * 256 + threadIdx.x;
  if (e >= nE) return;
  int d = dst[e];
  atomicAdd(&s[d], expf(edge_score(el, er, src[e], d) - m[d]));
}

__global__ __launch_bounds__(128) void edge_aggregate_kernel(
    const float* __restrict__ f, const float* __restrict__ el,
    const float* __restrict__ er, const float* __restrict__ m,
    const float* __restrict__ s, const int* __restrict__ src,
    const int* __restrict__ dst, float* __restrict__ out, int nE) {
  int e = blockIdx.x;
  int d = threadIdx.x;
  int sv = src[e], dv = dst[e];
  float alpha = expf(edge_score(el, er, sv, dv) - m[dv]) / s[dv];
  atomicAdd(&out[(size_t)dv * 128 + d], alpha * f[(size_t)sv * 128 + d]);
}

__global__ void bias_relu_kernel(float* __restrict__ x,
                                 const float* __restrict__ b, int total) {
  int i = blockIdx.x * 256 + threadIdx.x;
  if (i >= total) return;
  x[i] = fmaxf(x[i] + b[i & 127], 0.f);
}

// ---------------- sort pooling ----------------
__global__ __launch_bounds__(64) void row_max_kernel(const float* __restrict__ x,
                                                     float* __restrict__ key) {
  int node = blockIdx.x, lane = threadIdx.x;
  float v = fmaxf(x[(size_t)node * 128 + lane], x[(size_t)node * 128 + 64 + lane]);
#pragma unroll
  for (int off = 32; off; off >>= 1) v = fmaxf(v, __shfl_down(v, off));
  if (lane == 0) key[node] = v;
}

__global__ __launch_bounds__(64) void select_topk_kernel(
    const float* __restrict__ key, int* __restrict__ sel) {
  __shared__ float keys[NPG];
  int g = blockIdx.x, t = threadIdx.x;
  keys[t] = key[(size_t)g * NPG + t];
  __syncthreads();
  float myk = keys[t];
  int rank = 0;
  for (int j = 0; j < NPG; ++j) {
    float kj = keys[j];
    rank += (kj > myk) || (kj == myk && j < t);
  }
  if (rank < KK) sel[g * KK + rank] = t;
}

__global__ __launch_bounds__(128) void sort_rows_kernel(
    const float* __restrict__ x, const int* __restrict__ sel,
    float* __restrict__ xp) {
  __shared__ float v[128];
  int b = blockIdx.x;
  int t = threadIdx.x;
  int g = b >> 3, r = b & 7;
  int node = sel[b];
  v[t] = x[(size_t)(g * NPG + node) * 128 + t];
  __syncthreads();
  for (int k = 2; k <= 128; k <<= 1) {
    for (int j = k >> 1; j > 0; j >>= 1) {
      int ixj = t ^ j;
      if (ixj > t) {
        float a = v[t], bb = v[ixj];
        bool asc = ((t & k) == 0);
        if (asc ? (a > bb) : (a < bb)) { v[t] = bb; v[ixj] = a; }
      }
      __syncthreads();
    }
  }
  xp[(size_t)g * (KK * 128) + r * 128 + t] = v[t];
}

// ---------------- classifier ----------------
__global__ __launch_bounds__(64) void classifier_kernel(
    const float* __restrict__ x, const float* __restrict__ Wc,
    const float* __restrict__ bc, float* __restrict__ out) {
  int g = blockIdx.x, lane = threadIdx.x;
  float v1 = x[(size_t)g * 128 + lane];
  float v2 = x[(size_t)g * 128 + 64 + lane];
  float a0 = v1 * Wc[lane * 2 + 0] + v2 * Wc[(64 + lane) * 2 + 0];
  float a1 = v1 * Wc[lane * 2 + 1] + v2 * Wc[(64 + lane) * 2 + 1];
#pragma unroll
  for (int off = 32; off; off >>= 1) {
    a0 += __shfl_down(a0, off);
    a1 += __shfl_down(a1, off);
  }
  if (lane == 0) {
    out[g * 2 + 0] = a0 + bc[0];
    out[g * 2 + 1] = a1 + bc[1];
  }
}

// ---------------- launcher ----------------
extern "C" void kernel_launch(void* const* d_in, const int* in_sizes, int n_in,
                              void* d_out, int out_size, void* d_ws, size_t ws_size,
                              hipStream_t stream) {
  const size_t BASE_FLOATS = (size_t)NN * DD * 2 + (size_t)NN * 4;  // X,F,el,er,mx,sm
  const size_t CSR_INTS = (size_t)(NN + 1) + NN + EE + 128;          // row_ptr,cursor,eidx,part
  if (ws_size < BASE_FLOATS * sizeof(float)) {
    hipMemsetAsync(d_out, 0, (size_t)out_size * sizeof(float), stream);
    return;
  }
  const bool use_csr = ws_size >= BASE_FLOATS * sizeof(float) + CSR_INTS * sizeof(int);

  const int* h      = (const int*)d_in[0];
  const int* g_src  = (const int*)d_in[1];
  const int* g_dst  = (const int*)d_in[2];
  const int* fg_src = (const int*)d_in[3];
  const int* fg_dst = (const int*)d_in[4];
  const float* temb = (const float*)d_in[5];
  const float* W1 = (const float*)d_in[6];
  const float* al1 = (const float*)d_in[7];
  const float* ar1 = (const float*)d_in[8];
  const float* b1 = (const float*)d_in[9];
  const float* W2 = (const float*)d_in[10];
  const float* al2 = (const float*)d_in[11];
  const float* ar2 = (const float*)d_in[12];
  const float* b2 = (const float*)d_in[13];
  const float* W3 = (const float*)d_in[14];
  const float* al3 = (const float*)d_in[15];
  const float* ar3 = (const float*)d_in[16];
  const float* b3 = (const float*)d_in[17];
  const float* Wf = (const float*)d_in[18];
  const float* bfv = (const float*)d_in[19];
  const float* Wl = (const float*)d_in[20];
  const float* bl = (const float*)d_in[21];
  const float* Wl1 = (const float*)d_in[22];
  const float* bl1 = (const float*)d_in[23];
  const float* Wc = (const float*)d_in[24];
  const float* bc = (const float*)d_in[25];
  float* out = (float*)d_out;

  // ---- workspace layout ----
  float* ws = (float*)d_ws;
  float* X  = ws;
  float* F  = X + (size_t)NN * DD;
  float* el = F + (size_t)NN * DD;
  float* er = el + NN;
  float* mx = er + NN;
  float* sm = mx + NN;
  int* row_ptr = (int*)(sm + NN);
  int* cursor  = row_ptr + NN + 1;
  int* eidx    = cursor + NN;
  int* part    = eidx + EE;
  // carved from F once F is dead (after layer-2 aggregation):
  float* xp   = F;
  float* f3   = F + 2097152;
  float* g3   = f3 + (size_t)GG * DD;
  float* t1   = g3 + (size_t)GG * DD;
  float* t2   = t1 + (size_t)GG * DD;
  float* keyb = t2 + (size_t)GG * DD;
  int*   sel  = (int*)(keyb + NN);

  const int totalND = NN * DD;

  if (use_csr) {
    // ---- build CSR of inner graph by dst (reused by both GAT layers) ----
    zero_int_kernel<<<NN / 256, 256, 0, stream>>>(cursor, NN);
    hist_kernel<<<EE / 256, 256, 0, stream>>>(g_dst, cursor, EE);
    scan_block_kernel<<<NN / 1024, 256, 0, stream>>>(cursor, row_ptr, part);
    scan_part_kernel<<<1, 128, 0, stream>>>(part);
    scan_add_kernel<<<(NN + 255) / 256, 256, 0, stream>>>(row_ptr, part, NN, EE);
    zero_int_kernel<<<NN / 256, 256, 0, stream>>>(cursor, NN);
    scatter_kernel<<<EE / 256, 256, 0, stream>>>(g_dst, row_ptr, cursor, eidx, EE);

    // layer 1: F = relu(temb[h]) @ W1 fused with embed-gather + el/er epilogue
    gemm128_fused<1, 1><<<NN / 64, 256, 0, stream>>>(
        nullptr, temb, h, W1, nullptr, F, al1, ar1, el, er, nullptr);
    gat_aggregate_csr_kernel<<<NN, 128, 0, stream>>>(F, el, er, row_ptr, eidx, g_src, b1, X);

    // layer 2
    gemm128_fused<0, 1><<<NN / 64, 256, 0, stream>>>(
        X, nullptr, nullptr, W2, nullptr, F, al2, ar2, el, er, nullptr);
    gat_aggregate_csr_kernel<<<NN, 128, 0, stream>>>(F, el, er, row_ptr, eidx, g_src, b2, X);

    // linear_forward in-place + fused row-max
    gemm128_fused<0, 2><<<NN / 64, 256, 0, stream>>>(
        X, nullptr, nullptr, Wf, bfv, X, nullptr, nullptr, nullptr, nullptr, keyb);
  } else {
    embed_relu_kernel<<<totalND / 256, 256, 0, stream>>>(temb, h, X, totalND);
    auto gat_inner = [&](const float* W, const float* al, const float* ar, const float* bb) {
      gemm_kernel<DD, 8><<<NN / 8, 128, 0, stream>>>(X, W, nullptr, F, 0);
      attn_logits_kernel<<<NN, 64, 0, stream>>>(F, al, ar, el, er);
      init_softmax_kernel<<<(NN + 255) / 256, 256, 0, stream>>>(mx, sm, NN);
      fill_f32_kernel<<<totalND / 256, 256, 0, stream>>>(X, 0.f, totalND);
      edge_max_kernel<<<(EE + 255) / 256, 256, 0, stream>>>(el, er, g_src, g_dst, mx, EE);
      edge_expsum_kernel<<<(EE + 255) / 256, 256, 0, stream>>>(el, er, mx, g_src, g_dst, sm, EE);
      edge_aggregate_kernel<<<EE, 128, 0, stream>>>(F, el, er, mx, sm, g_src, g_dst, X, EE);
      bias_relu_kernel<<<totalND / 256, 256, 0, stream>>>(X, bb, totalND);
    };
    gat_inner(W1, al1, ar1, b1);
    gat_inner(W2, al2, ar2, b2);
    gemm_kernel<DD, 8><<<NN / 8, 128, 0, stream>>>(X, Wf, bfv, X, 1);
    row_max_kernel<<<NN, 64, 0, stream>>>(X, keyb);
  }

  // sort pooling -> xp [G, 1024]
  select_topk_kernel<<<GG, 64, 0, stream>>>(keyb, sel);
  sort_rows_kernel<<<GG * KK, 128, 0, stream>>>(X, sel, xp);

  // outer GAT over fg (atomic path — small)
  gemm_kernel<KK * DD, 8><<<GG / 8, 128, 0, stream>>>(xp, W3, nullptr, f3, 0);
  attn_logits_kernel<<<GG, 64, 0, stream>>>(f3, al3, ar3, el, er);
  init_softmax_kernel<<<(GG + 255) / 256, 256, 0, stream>>>(mx, sm, GG);
  fill_f32_kernel<<<(GG * DD + 255) / 256, 256, 0, stream>>>(g3, 0.f, GG * DD);
  edge_max_kernel<<<(EFN + 255) / 256, 256, 0, stream>>>(el, er, fg_src, fg_dst, mx, EFN);
  edge_expsum_kernel<<<(EFN + 255) / 256, 256, 0, stream>>>(el, er, mx, fg_src, fg_dst, sm, EFN);
  edge_aggregate_kernel<<<EFN, 128, 0, stream>>>(f3, el, er, mx, sm, fg_src, fg_dst, g3, EFN);
  bias_relu_kernel<<<(GG * DD + 255) / 256, 256, 0, stream>>>(g3, b3, GG * DD);

  // t1 = relu(g3 @ Wl + bl); t2 = relu(t1 @ Wl1 + bl1)
  gemm_kernel<DD, 8><<<GG / 8, 128, 0, stream>>>(g3, Wl, bl, t1, 1);
  gemm_kernel<DD, 8><<<GG / 8, 128, 0, stream>>>(t1, Wl1, bl1, t2, 1);

  // classifier -> fp32 out [G,2]
  classifier_kernel<<<GG, 64, 0, stream>>>(t2, Wc, bc, out);
}

// Round 10
// 872.596 us; speedup vs baseline: 3.3835x; 1.0088x over previous
//
#include <hip/hip_runtime.h>
#include <math.h>

#define NN   131072   // total inner nodes
#define GG   2048     // graphs
#define NPG  64       // nodes per graph
#define EE   1048576  // inner edges
#define EFN  32768    // outer edges
#define DD   128      // feature dim
#define KK   8        // sortpool k

// ---------------- utility ----------------
__global__ void fill_f32_kernel(float* __restrict__ p, float v, int nElems) {
  int i = blockIdx.x * 256 + threadIdx.x;
  if (i < nElems) p[i] = v;
}

__global__ void zero_int_kernel(int* __restrict__ p, int nElems) {
  int i = blockIdx.x * 256 + threadIdx.x;
  if (i < nElems) p[i] = 0;
}

__global__ void init_softmax_kernel(float* __restrict__ mx, float* __restrict__ sm, int nElems) {
  int i = blockIdx.x * 256 + threadIdx.x;
  if (i < nElems) { mx[i] = -INFINITY; sm[i] = 0.f; }
}

// x[i] = relu(token_emb[h[node]][d])   (fallback path only)
__global__ void embed_relu_kernel(const float* __restrict__ temb,
                                  const int* __restrict__ h,
                                  float* __restrict__ x, int total) {
  int i = blockIdx.x * 256 + threadIdx.x;
  if (i >= total) return;
  int node = i >> 7, d = i & 127;
  x[i] = fmaxf(temb[h[node] * DD + d], 0.f);
}

// ---------------- small / generic GEMM (outer graph, fallback) ----------------
template <int KD, int ROWS>
__global__ __launch_bounds__(128) void gemm_kernel(
    const float* __restrict__ A, const float* __restrict__ W,
    const float* __restrict__ bias, float* __restrict__ out,
    int relu_flag) {
  __shared__ float As[ROWS * KD];
  const int row0 = blockIdx.x * ROWS;
  const int tid = threadIdx.x;
  for (int i = tid; i < ROWS * KD; i += 128) As[i] = A[(size_t)row0 * KD + i];
  __syncthreads();
  float acc[ROWS];
#pragma unroll
  for (int r = 0; r < ROWS; r++) acc[r] = 0.f;
  for (int k = 0; k < KD; k++) {
    float w = W[k * 128 + tid];
#pragma unroll
    for (int r = 0; r < ROWS; r++) acc[r] += As[r * KD + k] * w;
  }
  float b = bias ? bias[tid] : 0.f;
#pragma unroll
  for (int r = 0; r < ROWS; r++) {
    float v = acc[r] + b;
    if (relu_flag) v = fmaxf(v, 0.f);
    out[(size_t)(row0 + r) * 128 + tid] = v;
  }
}

// ---------------- fused tiled GEMM: out[M,128] = act(A)[M,128] @ W[128,128] ----------------
template <int SRC_MODE, int EPI>
__global__ __launch_bounds__(256) void gemm128_fused(
    const float* __restrict__ A, const float* __restrict__ temb,
    const int* __restrict__ hidx, const float* __restrict__ W,
    const float* __restrict__ bias, float* __restrict__ out,
    const float* __restrict__ al, const float* __restrict__ ar,
    float* __restrict__ el, float* __restrict__ er,
    float* __restrict__ keyb) {
  __shared__ float As[64 * 128];
  const int t = threadIdx.x;
  const int row0 = blockIdx.x * 64;
  for (int idx = t; idx < 64 * 32; idx += 256) {
    int r = idx >> 5, c4 = (idx & 31) << 2;
    if (SRC_MODE == 1) {
      const float* src = temb + (size_t)hidx[row0 + r] * 128 + c4;
      float4 v = *(const float4*)src;
      v.x = fmaxf(v.x, 0.f); v.y = fmaxf(v.y, 0.f);
      v.z = fmaxf(v.z, 0.f); v.w = fmaxf(v.w, 0.f);
      *(float4*)&As[r * 128 + c4] = v;
    } else {
      *(float4*)&As[r * 128 + c4] = *(const float4*)(A + (size_t)(row0 + r) * 128 + c4);
    }
  }
  __syncthreads();
  const int rg = t >> 5, cg = t & 31;
  const int r0 = rg * 8, c0 = cg * 4;
  float acc[8][4];
#pragma unroll
  for (int i = 0; i < 8; i++)
#pragma unroll
    for (int j = 0; j < 4; j++) acc[i][j] = 0.f;
  for (int k = 0; k < 128; k += 4) {
    float4 w0 = *(const float4*)(W + (size_t)(k + 0) * 128 + c0);
    float4 w1 = *(const float4*)(W + (size_t)(k + 1) * 128 + c0);
    float4 w2 = *(const float4*)(W + (size_t)(k + 2) * 128 + c0);
    float4 w3 = *(const float4*)(W + (size_t)(k + 3) * 128 + c0);
#pragma unroll
    for (int i = 0; i < 8; i++) {
      float4 a = *(const float4*)&As[(r0 + i) * 128 + k];
      acc[i][0] += a.x * w0.x + a.y * w1.x + a.z * w2.x + a.w * w3.x;
      acc[i][1] += a.x * w0.y + a.y * w1.y + a.z * w2.y + a.w * w3.y;
      acc[i][2] += a.x * w0.z + a.y * w1.z + a.z * w2.z + a.w * w3.z;
      acc[i][3] += a.x * w0.w + a.y * w1.w + a.z * w2.w + a.w * w3.w;
    }
  }
  if (EPI == 0) {
#pragma unroll
    for (int i = 0; i < 8; i++) {
      float4 v = make_float4(acc[i][0], acc[i][1], acc[i][2], acc[i][3]);
      *(float4*)(out + (size_t)(row0 + r0 + i) * 128 + c0) = v;
    }
  } else if (EPI == 1) {
    float4 alv = *(const float4*)(al + c0);
    float4 arv = *(const float4*)(ar + c0);
#pragma unroll
    for (int i = 0; i < 8; i++) {
      float4 v = make_float4(acc[i][0], acc[i][1], acc[i][2], acc[i][3]);
      *(float4*)(out + (size_t)(row0 + r0 + i) * 128 + c0) = v;
      float pl = v.x * alv.x + v.y * alv.y + v.z * alv.z + v.w * alv.w;
      float pr = v.x * arv.x + v.y * arv.y + v.z * arv.z + v.w * arv.w;
#pragma unroll
      for (int off = 16; off; off >>= 1) {
        pl += __shfl_down(pl, off, 32);
        pr += __shfl_down(pr, off, 32);
      }
      if (cg == 0) {
        el[row0 + r0 + i] = pl;
        er[row0 + r0 + i] = pr;
      }
    }
  } else {  // EPI == 2
    float4 bv = *(const float4*)(bias + c0);
#pragma unroll
    for (int i = 0; i < 8; i++) {
      float4 v;
      v.x = fmaxf(acc[i][0] + bv.x, 0.f);
      v.y = fmaxf(acc[i][1] + bv.y, 0.f);
      v.z = fmaxf(acc[i][2] + bv.z, 0.f);
      v.w = fmaxf(acc[i][3] + bv.w, 0.f);
      *(float4*)(out + (size_t)(row0 + r0 + i) * 128 + c0) = v;
      float pm = fmaxf(fmaxf(v.x, v.y), fmaxf(v.z, v.w));
#pragma unroll
      for (int off = 16; off; off >>= 1) pm = fmaxf(pm, __shfl_down(pm, off, 32));
      if (cg == 0) keyb[row0 + r0 + i] = pm;
    }
  }
}

// ---------------- attention logits (outer graph, fallback) ----------------
__global__ __launch_bounds__(64) void attn_logits_kernel(
    const float* __restrict__ f, const float* __restrict__ al,
    const float* __restrict__ ar, float* __restrict__ el,
    float* __restrict__ er) {
  int node = blockIdx.x, lane = threadIdx.x;
  float v1 = f[(size_t)node * 128 + lane];
  float v2 = f[(size_t)node * 128 + 64 + lane];
  float sl = v1 * al[lane] + v2 * al[64 + lane];
  float sr = v1 * ar[lane] + v2 * ar[64 + lane];
#pragma unroll
  for (int off = 32; off; off >>= 1) {
    sl += __shfl_down(sl, off);
    sr += __shfl_down(sr, off);
  }
  if (lane == 0) { el[node] = sl; er[node] = sr; }
}

// ---------------- CSR build ----------------
__global__ void hist_kernel(const int* __restrict__ dst, int* __restrict__ cnt, int nE) {
  int e = blockIdx.x * 256 + threadIdx.x;
  if (e < nE) atomicAdd(&cnt[dst[e]], 1);
}

__global__ __launch_bounds__(256) void scan_block_kernel(
    const int* __restrict__ cnt, int* __restrict__ excl, int* __restrict__ part) {
  __shared__ int s[256];
  int blk = blockIdx.x, tid = threadIdx.x;
  int base = blk * 1024 + tid * 4;
  int a0 = cnt[base], a1 = cnt[base + 1], a2 = cnt[base + 2], a3 = cnt[base + 3];
  int tsum = a0 + a1 + a2 + a3;
  s[tid] = tsum; __syncthreads();
  for (int off = 1; off < 256; off <<= 1) {
    int v = (tid >= off) ? s[tid - off] : 0;
    __syncthreads();
    s[tid] += v;
    __syncthreads();
  }
  int texcl = s[tid] - tsum;
  excl[base]     = texcl;
  excl[base + 1] = texcl + a0;
  excl[base + 2] = texcl + a0 + a1;
  excl[base + 3] = texcl + a0 + a1 + a2;
  if (tid == 255) part[blk] = s[255];
}

__global__ __launch_bounds__(128) void scan_part_kernel(int* __restrict__ part) {
  __shared__ int s[128];
  int tid = threadIdx.x;
  int orig = part[tid];
  s[tid] = orig; __syncthreads();
  for (int off = 1; off < 128; off <<= 1) {
    int v = (tid >= off) ? s[tid - off] : 0;
    __syncthreads();
    s[tid] += v;
    __syncthreads();
  }
  part[tid] = s[tid] - orig;
}

__global__ void scan_add_kernel(int* __restrict__ row_ptr, const int* __restrict__ part,
                                int n, int total) {
  int i = blockIdx.x * 256 + threadIdx.x;
  if (i < n) row_ptr[i] += part[i >> 10];
  if (i == 0) row_ptr[n] = total;
}

__global__ void scatter_kernel(const int* __restrict__ dst, const int* __restrict__ row_ptr,
                               int* __restrict__ cursor, int* __restrict__ eidx, int nE) {
  int e = blockIdx.x * 256 + threadIdx.x;
  if (e >= nE) return;
  int d = dst[e];
  int pos = row_ptr[d] + atomicAdd(&cursor[d], 1);
  eidx[pos] = e;
}

// ---------------- fused CSR GAT aggregation ----------------
// One 128-thread block per dst node. Fast path (n<=128): block softmax, then
// float4 gather with 4 column-groups handling edges j%4==g and manual 2-way
// unroll -> up to 8 rows in flight per block; LDS cross-group reduction.
__global__ __launch_bounds__(128) void gat_aggregate_csr_kernel(
    const float* __restrict__ F, const float* __restrict__ el,
    const float* __restrict__ er, const int* __restrict__ row_ptr,
    const int* __restrict__ eidx, const int* __restrict__ src,
    const float* __restrict__ bias, float* __restrict__ outX) {
  int d = blockIdx.x, tid = threadIdx.x;
  int beg = row_ptr[d], end = row_ptr[d + 1];
  int n = end - beg;
  if (n == 0) { outX[(size_t)d * 128 + tid] = fmaxf(bias[tid], 0.f); return; }
  __shared__ float red[128];
  __shared__ float wts[128];
  __shared__ int   svs[128];
  __shared__ float accs[4][128];
  float er_d = er[d];
  if (n <= 128) {  // fast path (avg degree 8 — essentially always)
    float sc = -INFINITY; int sv = 0;
    if (tid < n) {
      sv = src[eidx[beg + tid]];
      float v = el[sv] + er_d;
      sc = v > 0.f ? v : 0.2f * v;
    }
    red[tid] = sc; __syncthreads();
    for (int off = 64; off; off >>= 1) {
      if (tid < off) red[tid] = fmaxf(red[tid], red[tid + off]);
      __syncthreads();
    }
    float m = red[0]; __syncthreads();
    float ex = (tid < n) ? expf(sc - m) : 0.f;
    red[tid] = ex; __syncthreads();
    for (int off = 64; off; off >>= 1) {
      if (tid < off) red[tid] += red[tid + off];
      __syncthreads();
    }
    float s = red[0]; __syncthreads();
    wts[tid] = ex / s;
    svs[tid] = sv;
    __syncthreads();
    const int g = tid >> 5, l = tid & 31;
    float4 acc = make_float4(0.f, 0.f, 0.f, 0.f);
    int j = g;
    for (; j + 8 <= n; j += 8) {
      float4 f0 = *(const float4*)&F[(size_t)svs[j] * 128 + 4 * l];
      float4 f1 = *(const float4*)&F[(size_t)svs[j + 4] * 128 + 4 * l];
      float w0 = wts[j], w1 = wts[j + 4];
      acc.x += w0 * f0.x + w1 * f1.x;
      acc.y += w0 * f0.y + w1 * f1.y;
      acc.z += w0 * f0.z + w1 * f1.z;
      acc.w += w0 * f0.w + w1 * f1.w;
    }
    for (; j < n; j += 4) {
      float4 f0 = *(const float4*)&F[(size_t)svs[j] * 128 + 4 * l];
      float w0 = wts[j];
      acc.x += w0 * f0.x; acc.y += w0 * f0.y;
      acc.z += w0 * f0.z; acc.w += w0 * f0.w;
    }
    accs[g][4 * l + 0] = acc.x;
    accs[g][4 * l + 1] = acc.y;
    accs[g][4 * l + 2] = acc.z;
    accs[g][4 * l + 3] = acc.w;
    __syncthreads();
    float v = accs[0][tid] + accs[1][tid] + accs[2][tid] + accs[3][tid] + bias[tid];
    outX[(size_t)d * 128 + tid] = fmaxf(v, 0.f);
  } else {  // chunked general path (degree > 128 — rare)
    float b = bias[tid];
    float acc = 0.f;
    float lm = -INFINITY;
    for (int t = tid; t < n; t += 128) {
      int sv = src[eidx[beg + t]];
      float v = el[sv] + er_d;
      v = v > 0.f ? v : 0.2f * v;
      lm = fmaxf(lm, v);
    }
    red[tid] = lm; __syncthreads();
    for (int off = 64; off; off >>= 1) {
      if (tid < off) red[tid] = fmaxf(red[tid], red[tid + off]);
      __syncthreads();
    }
    float m = red[0]; __syncthreads();
    float ls = 0.f;
    for (int t = tid; t < n; t += 128) {
      int sv = src[eidx[beg + t]];
      float v = el[sv] + er_d;
      v = v > 0.f ? v : 0.2f * v;
      ls += expf(v - m);
    }
    red[tid] = ls; __syncthreads();
    for (int off = 64; off; off >>= 1) {
      if (tid < off) red[tid] += red[tid + off];
      __syncthreads();
    }
    float s = red[0]; __syncthreads();
    for (int base = 0; base < n; base += 128) {
      int t = base + tid;
      if (t < n) {
        int sv = src[eidx[beg + t]];
        float v = el[sv] + er_d;
        v = v > 0.f ? v : 0.2f * v;
        wts[tid] = expf(v - m) / s;
        svs[tid] = sv;
      }
      __syncthreads();
      int cnt = min(128, n - base);
      for (int j = 0; j < cnt; ++j)
        acc += wts[j] * F[(size_t)svs[j] * 128 + tid];
      __syncthreads();
    }
    outX[(size_t)d * 128 + tid] = fmaxf(acc + b, 0.f);
  }
}

// ---------------- atomic-path edge kernels (outer graph + fallback) ----------------
static __device__ __forceinline__ void atomicMaxF(float* addr, float v) {
  int iv = __float_as_int(v);
  if (iv >= 0) atomicMax((int*)addr, iv);
  else atomicMin((unsigned int*)addr, (unsigned int)iv);
}

static __device__ __forceinline__ float edge_score(const float* el, const float* er,
                                                   int sv, int dv) {
  float v = el[sv] + er[dv];
  return v > 0.f ? v : 0.2f * v;
}

__global__ void edge_max_kernel(const float* __restrict__ el,
                                const float* __restrict__ er,
                                const int* __restrict__ src,
                                const int* __restrict__ dst,
                                float* __restrict__ m, int nE) {
  int e = blockIdx.x * 256 + threadIdx.x;
  if (e >= nE) return;
  atomicMaxF(&m[dst[e]], edge_score(el, er, src[e], dst[e]));
}

__global__ void edge_expsum_kernel(const float* __restrict__ el,
                                   const float* __restrict__ er,
                                   const float* __restrict__ m,
                                   const int* __restrict__ src,
                                   const int* __restrict__ dst,
                                   float* __restrict__ s, int nE) {
  int e = blockIdx.x * 256 + threadIdx.x;
  if (e >= nE) return;
  int d = dst[e];
  atomicAdd(&s[d], expf(edge_score(el, er, src[e], d) - m[d]));
}

__global__ __launch_bounds__(128) void edge_aggregate_kernel(
    const float* __restrict__ f, const float* __restrict__ el,
    const float* __restrict__ er, const float* __restrict__ m,
    const float* __restrict__ s, const int* __restrict__ src,
    const int* __restrict__ dst, float* __restrict__ out, int nE) {
  int e = blockIdx.x;
  int d = threadIdx.x;
  int sv = src[e], dv = dst[e];
  float alpha = expf(edge_score(el, er, sv, dv) - m[dv]) / s[dv];
  atomicAdd(&out[(size_t)dv * 128 + d], alpha * f[(size_t)sv * 128 + d]);
}

__global__ void bias_relu_kernel(float* __restrict__ x,
                                 const float* __restrict__ b, int total) {
  int i = blockIdx.x * 256 + threadIdx.x;
  if (i >= total) return;
  x[i] = fmaxf(x[i] + b[i & 127], 0.f);
}

// ---------------- sort pooling ----------------
__global__ __launch_bounds__(64) void row_max_kernel(const float* __restrict__ x,
                                                     float* __restrict__ key) {
  int node = blockIdx.x, lane = threadIdx.x;
  float v = fmaxf(x[(size_t)node * 128 + lane], x[(size_t)node * 128 + 64 + lane]);
#pragma unroll
  for (int off = 32; off; off >>= 1) v = fmaxf(v, __shfl_down(v, off));
  if (lane == 0) key[node] = v;
}

__global__ __launch_bounds__(64) void select_topk_kernel(
    const float* __restrict__ key, int* __restrict__ sel) {
  __shared__ float keys[NPG];
  int g = blockIdx.x, t = threadIdx.x;
  keys[t] = key[(size_t)g * NPG + t];
  __syncthreads();
  float myk = keys[t];
  int rank = 0;
  for (int j = 0; j < NPG; ++j) {
    float kj = keys[j];
    rank += (kj > myk) || (kj == myk && j < t);
  }
  if (rank < KK) sel[g * KK + rank] = t;
}

__global__ __launch_bounds__(128) void sort_rows_kernel(
    const float* __restrict__ x, const int* __restrict__ sel,
    float* __restrict__ xp) {
  __shared__ float v[128];
  int b = blockIdx.x;
  int t = threadIdx.x;
  int g = b >> 3, r = b & 7;
  int node = sel[b];
  v[t] = x[(size_t)(g * NPG + node) * 128 + t];
  __syncthreads();
  for (int k = 2; k <= 128; k <<= 1) {
    for (int j = k >> 1; j > 0; j >>= 1) {
      int ixj = t ^ j;
      if (ixj > t) {
        float a = v[t], bb = v[ixj];
        bool asc = ((t & k) == 0);
        if (asc ? (a > bb) : (a < bb)) { v[t] = bb; v[ixj] = a; }
      }
      __syncthreads();
    }
  }
  xp[(size_t)g * (KK * 128) + r * 128 + t] = v[t];
}

// ---------------- classifier ----------------
__global__ __launch_bounds__(64) void classifier_kernel(
    const float* __restrict__ x, const float* __restrict__ Wc,
    const float* __restrict__ bc, float* __restrict__ out) {
  int g = blockIdx.x, lane = threadIdx.x;
  float v1 = x[(size_t)g * 128 + lane];
  float v2 = x[(size_t)g * 128 + 64 + lane];
  float a0 = v1 * Wc[lane * 2 + 0] + v2 * Wc[(64 + lane) * 2 + 0];
  float a1 = v1 * Wc[lane * 2 + 1] + v2 * Wc[(64 + lane) * 2 + 1];
#pragma unroll
  for (int off = 32; off; off >>= 1) {
    a0 += __shfl_down(a0, off);
    a1 += __shfl_down(a1, off);
  }
  if (lane == 0) {
    out[g * 2 + 0] = a0 + bc[0];
    out[g * 2 + 1] = a1 + bc[1];
  }
}

// ---------------- launcher ----------------
extern "C" void kernel_launch(void* const* d_in, const int* in_sizes, int n_in,
                              void* d_out, int out_size, void* d_ws, size_t ws_size,
                              hipStream_t stream) {
  const size_t BASE_FLOATS = (size_t)NN * DD * 2 + (size_t)NN * 4;  // X,F,el,er,mx,sm
  const size_t CSR_INTS = (size_t)(NN + 1) + NN + EE + 128;          // row_ptr,cursor,eidx,part
  if (ws_size < BASE_FLOATS * sizeof(float)) {
    hipMemsetAsync(d_out, 0, (size_t)out_size * sizeof(float), stream);
    return;
  }
  const bool use_csr = ws_size >= BASE_FLOATS * sizeof(float) + CSR_INTS * sizeof(int);

  const int* h      = (const int*)d_in[0];
  const int* g_src  = (const int*)d_in[1];
  const int* g_dst  = (const int*)d_in[2];
  const int* fg_src = (const int*)d_in[3];
  const int* fg_dst = (const int*)d_in[4];
  const float* temb = (const float*)d_in[5];
  const float* W1 = (const float*)d_in[6];
  const float* al1 = (const float*)d_in[7];
  const float* ar1 = (const float*)d_in[8];
  const float* b1 = (const float*)d_in[9];
  const float* W2 = (const float*)d_in[10];
  const float* al2 = (const float*)d_in[11];
  const float* ar2 = (const float*)d_in[12];
  const float* b2 = (const float*)d_in[13];
  const float* W3 = (const float*)d_in[14];
  const float* al3 = (const float*)d_in[15];
  const float* ar3 = (const float*)d_in[16];
  const float* b3 = (const float*)d_in[17];
  const float* Wf = (const float*)d_in[18];
  const float* bfv = (const float*)d_in[19];
  const float* Wl = (const float*)d_in[20];
  const float* bl = (const float*)d_in[21];
  const float* Wl1 = (const float*)d_in[22];
  const float* bl1 = (const float*)d_in[23];
  const float* Wc = (const float*)d_in[24];
  const float* bc = (const float*)d_in[25];
  float* out = (float*)d_out;

  // ---- workspace layout ----
  float* ws = (float*)d_ws;
  float* X  = ws;
  float* F  = X + (size_t)NN * DD;
  float* el = F + (size_t)NN * DD;
  float* er = el + NN;
  float* mx = er + NN;
  float* sm = mx + NN;
  int* row_ptr = (int*)(sm + NN);
  int* cursor  = row_ptr + NN + 1;
  int* eidx    = cursor + NN;
  int* part    = eidx + EE;
  // carved from F once F is dead (after layer-2 aggregation):
  float* xp   = F;
  float* f3   = F + 2097152;
  float* g3   = f3 + (size_t)GG * DD;
  float* t1   = g3 + (size_t)GG * DD;
  float* t2   = t1 + (size_t)GG * DD;
  float* keyb = t2 + (size_t)GG * DD;
  int*   sel  = (int*)(keyb + NN);

  const int totalND = NN * DD;

  if (use_csr) {
    // ---- build CSR of inner graph by dst (reused by both GAT layers) ----
    zero_int_kernel<<<NN / 256, 256, 0, stream>>>(cursor, NN);
    hist_kernel<<<EE / 256, 256, 0, stream>>>(g_dst, cursor, EE);
    scan_block_kernel<<<NN / 1024, 256, 0, stream>>>(cursor, row_ptr, part);
    scan_part_kernel<<<1, 128, 0, stream>>>(part);
    scan_add_kernel<<<(NN + 255) / 256, 256, 0, stream>>>(row_ptr, part, NN, EE);
    zero_int_kernel<<<NN / 256, 256, 0, stream>>>(cursor, NN);
    scatter_kernel<<<EE / 256, 256, 0, stream>>>(g_dst, row_ptr, cursor, eidx, EE);

    // layer 1: F = relu(temb[h]) @ W1 fused with embed-gather + el/er epilogue
    gemm128_fused<1, 1><<<NN / 64, 256, 0, stream>>>(
        nullptr, temb, h, W1, nullptr, F, al1, ar1, el, er, nullptr);
    gat_aggregate_csr_kernel<<<NN, 128, 0, stream>>>(F, el, er, row_ptr, eidx, g_src, b1, X);

    // layer 2
    gemm128_fused<0, 1><<<NN / 64, 256, 0, stream>>>(
        X, nullptr, nullptr, W2, nullptr, F, al2, ar2, el, er, nullptr);
    gat_aggregate_csr_kernel<<<NN, 128, 0, stream>>>(F, el, er, row_ptr, eidx, g_src, b2, X);

    // linear_forward in-place + fused row-max
    gemm128_fused<0, 2><<<NN / 64, 256, 0, stream>>>(
        X, nullptr, nullptr, Wf, bfv, X, nullptr, nullptr, nullptr, nullptr, keyb);
  } else {
    embed_relu_kernel<<<totalND / 256, 256, 0, stream>>>(temb, h, X, totalND);
    auto gat_inner = [&](const float* W, const float* al, const float* ar, const float* bb) {
      gemm_kernel<DD, 8><<<NN / 8, 128, 0, stream>>>(X, W, nullptr, F, 0);
      attn_logits_kernel<<<NN, 64, 0, stream>>>(F, al, ar, el, er);
      init_softmax_kernel<<<(NN + 255) / 256, 256, 0, stream>>>(mx, sm, NN);
      fill_f32_kernel<<<totalND / 256, 256, 0, stream>>>(X, 0.f, totalND);
      edge_max_kernel<<<(EE + 255) / 256, 256, 0, stream>>>(el, er, g_src, g_dst, mx, EE);
      edge_expsum_kernel<<<(EE + 255) / 256, 256, 0, stream>>>(el, er, mx, g_src, g_dst, sm, EE);
      edge_aggregate_kernel<<<EE, 128, 0, stream>>>(F, el, er, mx, sm, g_src, g_dst, X, EE);
      bias_relu_kernel<<<totalND / 256, 256, 0, stream>>>(X, bb, totalND);
    };
    gat_inner(W1, al1, ar1, b1);
    gat_inner(W2, al2, ar2, b2);
    gemm_kernel<DD, 8><<<NN / 8, 128, 0, stream>>>(X, Wf, bfv, X, 1);
    row_max_kernel<<<NN, 64, 0, stream>>>(X, keyb);
  }

  // sort pooling -> xp [G, 1024]
  select_topk_kernel<<<GG, 64, 0, stream>>>(keyb, sel);
  sort_rows_kernel<<<GG * KK, 128, 0, stream>>>(X, sel, xp);

  // outer GAT over fg (atomic path — small)
  gemm_kernel<KK * DD, 8><<<GG / 8, 128, 0, stream>>>(xp, W3, nullptr, f3, 0);
  attn_logits_kernel<<<GG, 64, 0, stream>>>(f3, al3, ar3, el, er);
  init_softmax_kernel<<<(GG + 255) / 256, 256, 0, stream>>>(mx, sm, GG);
  fill_f32_kernel<<<(GG * DD + 255) / 256, 256, 0, stream>>>(g3, 0.f, GG * DD);
  edge_max_kernel<<<(EFN + 255) / 256, 256, 0, stream>>>(el, er, fg_src, fg_dst, mx, EFN);
  edge_expsum_kernel<<<(EFN + 255) / 256, 256, 0, stream>>>(el, er, mx, fg_src, fg_dst, sm, EFN);
  edge_aggregate_kernel<<<EFN, 128, 0, stream>>>(f3, el, er, mx, sm, fg_src, fg_dst, g3, EFN);
  bias_relu_kernel<<<(GG * DD + 255) / 256, 256, 0, stream>>>(g3, b3, GG * DD);

  // t1 = relu(g3 @ Wl + bl); t2 = relu(t1 @ Wl1 + bl1)
  gemm_kernel<DD, 8><<<GG / 8, 128, 0, stream>>>(g3, Wl, bl, t1, 1);
  gemm_kernel<DD, 8><<<GG / 8, 128, 0, stream>>>(t1, Wl1, bl1, t2, 1);

  // classifier -> fp32 out [G,2]
  classifier_kernel<<<GG, 64, 0, stream>>>(t2, Wc, bc, out);
}

// Round 11
// 776.670 us; speedup vs baseline: 3.8014x; 1.1235x over previous
//
#include <hip/hip_runtime.h>
#include <math.h>

#define NN   131072   // total inner nodes
#define GG   2048     // graphs
#define NPG  64       // nodes per graph
#define EE   1048576  // inner edges
#define EFN  32768    // outer edges
#define DD   128      // feature dim
#define KK   8        // sortpool k

// ---------------- utility ----------------
__global__ void fill_f32_kernel(float* __restrict__ p, float v, int nElems) {
  int i = blockIdx.x * 256 + threadIdx.x;
  if (i < nElems) p[i] = v;
}

__global__ void zero_int_kernel(int* __restrict__ p, int nElems) {
  int i = blockIdx.x * 256 + threadIdx.x;
  if (i < nElems) p[i] = 0;
}

__global__ void init_softmax_kernel(float* __restrict__ mx, float* __restrict__ sm, int nElems) {
  int i = blockIdx.x * 256 + threadIdx.x;
  if (i < nElems) { mx[i] = -INFINITY; sm[i] = 0.f; }
}

// x[i] = relu(token_emb[h[node]][d])   (fallback path only)
__global__ void embed_relu_kernel(const float* __restrict__ temb,
                                  const int* __restrict__ h,
                                  float* __restrict__ x, int total) {
  int i = blockIdx.x * 256 + threadIdx.x;
  if (i >= total) return;
  int node = i >> 7, d = i & 127;
  x[i] = fmaxf(temb[h[node] * DD + d], 0.f);
}

// ---------------- small / generic GEMM (outer graph, fallback) ----------------
template <int KD, int ROWS>
__global__ __launch_bounds__(128) void gemm_kernel(
    const float* __restrict__ A, const float* __restrict__ W,
    const float* __restrict__ bias, float* __restrict__ out,
    int relu_flag) {
  __shared__ float As[ROWS * KD];
  const int row0 = blockIdx.x * ROWS;
  const int tid = threadIdx.x;
  for (int i = tid; i < ROWS * KD; i += 128) As[i] = A[(size_t)row0 * KD + i];
  __syncthreads();
  float acc[ROWS];
#pragma unroll
  for (int r = 0; r < ROWS; r++) acc[r] = 0.f;
  for (int k = 0; k < KD; k++) {
    float w = W[k * 128 + tid];
#pragma unroll
    for (int r = 0; r < ROWS; r++) acc[r] += As[r * KD + k] * w;
  }
  float b = bias ? bias[tid] : 0.f;
#pragma unroll
  for (int r = 0; r < ROWS; r++) {
    float v = acc[r] + b;
    if (relu_flag) v = fmaxf(v, 0.f);
    out[(size_t)(row0 + r) * 128 + tid] = v;
  }
}

// ---------------- fused tiled GEMM: out[M,128] = act(A)[M,128] @ W[128,128] ----------------
template <int SRC_MODE, int EPI>
__global__ __launch_bounds__(256) void gemm128_fused(
    const float* __restrict__ A, const float* __restrict__ temb,
    const int* __restrict__ hidx, const float* __restrict__ W,
    const float* __restrict__ bias, float* __restrict__ out,
    const float* __restrict__ al, const float* __restrict__ ar,
    float* __restrict__ el, float* __restrict__ er,
    float* __restrict__ keyb) {
  __shared__ float As[64 * 128];
  const int t = threadIdx.x;
  const int row0 = blockIdx.x * 64;
  for (int idx = t; idx < 64 * 32; idx += 256) {
    int r = idx >> 5, c4 = (idx & 31) << 2;
    if (SRC_MODE == 1) {
      const float* src = temb + (size_t)hidx[row0 + r] * 128 + c4;
      float4 v = *(const float4*)src;
      v.x = fmaxf(v.x, 0.f); v.y = fmaxf(v.y, 0.f);
      v.z = fmaxf(v.z, 0.f); v.w = fmaxf(v.w, 0.f);
      *(float4*)&As[r * 128 + c4] = v;
    } else {
      *(float4*)&As[r * 128 + c4] = *(const float4*)(A + (size_t)(row0 + r) * 128 + c4);
    }
  }
  __syncthreads();
  const int rg = t >> 5, cg = t & 31;
  const int r0 = rg * 8, c0 = cg * 4;
  float acc[8][4];
#pragma unroll
  for (int i = 0; i < 8; i++)
#pragma unroll
    for (int j = 0; j < 4; j++) acc[i][j] = 0.f;
  for (int k = 0; k < 128; k += 4) {
    float4 w0 = *(const float4*)(W + (size_t)(k + 0) * 128 + c0);
    float4 w1 = *(const float4*)(W + (size_t)(k + 1) * 128 + c0);
    float4 w2 = *(const float4*)(W + (size_t)(k + 2) * 128 + c0);
    float4 w3 = *(const float4*)(W + (size_t)(k + 3) * 128 + c0);
#pragma unroll
    for (int i = 0; i < 8; i++) {
      float4 a = *(const float4*)&As[(r0 + i) * 128 + k];
      acc[i][0] += a.x * w0.x + a.y * w1.x + a.z * w2.x + a.w * w3.x;
      acc[i][1] += a.x * w0.y + a.y * w1.y + a.z * w2.y + a.w * w3.y;
      acc[i][2] += a.x * w0.z + a.y * w1.z + a.z * w2.z + a.w * w3.z;
      acc[i][3] += a.x * w0.w + a.y * w1.w + a.z * w2.w + a.w * w3.w;
    }
  }
  if (EPI == 0) {
#pragma unroll
    for (int i = 0; i < 8; i++) {
      float4 v = make_float4(acc[i][0], acc[i][1], acc[i][2], acc[i][3]);
      *(float4*)(out + (size_t)(row0 + r0 + i) * 128 + c0) = v;
    }
  } else if (EPI == 1) {
    float4 alv = *(const float4*)(al + c0);
    float4 arv = *(const float4*)(ar + c0);
#pragma unroll
    for (int i = 0; i < 8; i++) {
      float4 v = make_float4(acc[i][0], acc[i][1], acc[i][2], acc[i][3]);
      *(float4*)(out + (size_t)(row0 + r0 + i) * 128 + c0) = v;
      float pl = v.x * alv.x + v.y * alv.y + v.z * alv.z + v.w * alv.w;
      float pr = v.x * arv.x + v.y * arv.y + v.z * arv.z + v.w * arv.w;
#pragma unroll
      for (int off = 16; off; off >>= 1) {
        pl += __shfl_down(pl, off, 32);
        pr += __shfl_down(pr, off, 32);
      }
      if (cg == 0) {
        el[row0 + r0 + i] = pl;
        er[row0 + r0 + i] = pr;
      }
    }
  } else {  // EPI == 2
    float4 bv = *(const float4*)(bias + c0);
#pragma unroll
    for (int i = 0; i < 8; i++) {
      float4 v;
      v.x = fmaxf(acc[i][0] + bv.x, 0.f);
      v.y = fmaxf(acc[i][1] + bv.y, 0.f);
      v.z = fmaxf(acc[i][2] + bv.z, 0.f);
      v.w = fmaxf(acc[i][3] + bv.w, 0.f);
      *(float4*)(out + (size_t)(row0 + r0 + i) * 128 + c0) = v;
      float pm = fmaxf(fmaxf(v.x, v.y), fmaxf(v.z, v.w));
#pragma unroll
      for (int off = 16; off; off >>= 1) pm = fmaxf(pm, __shfl_down(pm, off, 32));
      if (cg == 0) keyb[row0 + r0 + i] = pm;
    }
  }
}

// ---------------- attention logits (outer graph, fallback) ----------------
__global__ __launch_bounds__(64) void attn_logits_kernel(
    const float* __restrict__ f, const float* __restrict__ al,
    const float* __restrict__ ar, float* __restrict__ el,
    float* __restrict__ er) {
  int node = blockIdx.x, lane = threadIdx.x;
  float v1 = f[(size_t)node * 128 + lane];
  float v2 = f[(size_t)node * 128 + 64 + lane];
  float sl = v1 * al[lane] + v2 * al[64 + lane];
  float sr = v1 * ar[lane] + v2 * ar[64 + lane];
#pragma unroll
  for (int off = 32; off; off >>= 1) {
    sl += __shfl_down(sl, off);
    sr += __shfl_down(sr, off);
  }
  if (lane == 0) { el[node] = sl; er[node] = sr; }
}

// ---------------- CSR build ----------------
__global__ void hist_kernel(const int* __restrict__ dst, int* __restrict__ cnt, int nE) {
  int e = blockIdx.x * 256 + threadIdx.x;
  if (e < nE) atomicAdd(&cnt[dst[e]], 1);
}

__global__ __launch_bounds__(256) void scan_block_kernel(
    const int* __restrict__ cnt, int* __restrict__ excl, int* __restrict__ part) {
  __shared__ int s[256];
  int blk = blockIdx.x, tid = threadIdx.x;
  int base = blk * 1024 + tid * 4;
  int a0 = cnt[base], a1 = cnt[base + 1], a2 = cnt[base + 2], a3 = cnt[base + 3];
  int tsum = a0 + a1 + a2 + a3;
  s[tid] = tsum; __syncthreads();
  for (int off = 1; off < 256; off <<= 1) {
    int v = (tid >= off) ? s[tid - off] : 0;
    __syncthreads();
    s[tid] += v;
    __syncthreads();
  }
  int texcl = s[tid] - tsum;
  excl[base]     = texcl;
  excl[base + 1] = texcl + a0;
  excl[base + 2] = texcl + a0 + a1;
  excl[base + 3] = texcl + a0 + a1 + a2;
  if (tid == 255) part[blk] = s[255];
}

__global__ __launch_bounds__(128) void scan_part_kernel(int* __restrict__ part) {
  __shared__ int s[128];
  int tid = threadIdx.x;
  int orig = part[tid];
  s[tid] = orig; __syncthreads();
  for (int off = 1; off < 128; off <<= 1) {
    int v = (tid >= off) ? s[tid - off] : 0;
    __syncthreads();
    s[tid] += v;
    __syncthreads();
  }
  part[tid] = s[tid] - orig;
}

__global__ void scan_add_kernel(int* __restrict__ row_ptr, const int* __restrict__ part,
                                int n, int total) {
  int i = blockIdx.x * 256 + threadIdx.x;
  if (i < n) row_ptr[i] += part[i >> 10];
  if (i == 0) row_ptr[n] = total;
}

// store src node id directly in adjacency (kills the src[eidx[]] indirection)
__global__ void scatter_kernel(const int* __restrict__ dst, const int* __restrict__ src,
                               const int* __restrict__ row_ptr,
                               int* __restrict__ cursor, int* __restrict__ adj_src, int nE) {
  int e = blockIdx.x * 256 + threadIdx.x;
  if (e >= nE) return;
  int d = dst[e];
  int pos = row_ptr[d] + atomicAdd(&cursor[d], 1);
  adj_src[pos] = src[e];
}

// ---------------- fused CSR GAT aggregation: one 64-lane wave per dst ----------------
// Softmax via wave shuffles (no LDS, no barriers); gather with lane = 2 cols
// (float2), weights/srcs broadcast by __shfl, 4-way unrolled (zero-wt padded).
__global__ __launch_bounds__(256) void gat_aggregate_csr_kernel(
    const float* __restrict__ F, const float* __restrict__ el,
    const float* __restrict__ er, const int* __restrict__ row_ptr,
    const int* __restrict__ adj_src,
    const float* __restrict__ bias, float* __restrict__ outX) {
  const int lane = threadIdx.x & 63;
  const int d = blockIdx.x * 4 + (threadIdx.x >> 6);
  const int c0 = lane * 2;
  int beg = row_ptr[d];
  int n = row_ptr[d + 1] - beg;
  float2 bv = *(const float2*)&bias[c0];
  if (n == 0) {
    float2 o; o.x = fmaxf(bv.x, 0.f); o.y = fmaxf(bv.y, 0.f);
    *(float2*)&outX[(size_t)d * 128 + c0] = o;
    return;
  }
  float er_d = er[d];
  float2 acc = make_float2(0.f, 0.f);
  if (n <= 64) {  // fast path: avg degree 8
    int sv = 0; float sc = -INFINITY;
    if (lane < n) {
      sv = adj_src[beg + lane];
      float v = el[sv] + er_d;
      sc = v > 0.f ? v : 0.2f * v;
    }
    float m = sc;
#pragma unroll
    for (int off = 32; off; off >>= 1) m = fmaxf(m, __shfl_xor(m, off));
    float ex = (lane < n) ? expf(sc - m) : 0.f;
    float s = ex;
#pragma unroll
    for (int off = 32; off; off >>= 1) s += __shfl_xor(s, off);
    float wt = ex / s;
    for (int j = 0; j < n; j += 4) {
      int   s0 = __shfl(sv, j);
      float w0 = __shfl(wt, j);
      int   j1 = (j + 1 < n) ? j + 1 : j;
      int   s1 = __shfl(sv, j1); float w1 = (j + 1 < n) ? __shfl(wt, j1) : 0.f;
      int   j2 = (j + 2 < n) ? j + 2 : j;
      int   s2 = __shfl(sv, j2); float w2 = (j + 2 < n) ? __shfl(wt, j2) : 0.f;
      int   j3 = (j + 3 < n) ? j + 3 : j;
      int   s3 = __shfl(sv, j3); float w3 = (j + 3 < n) ? __shfl(wt, j3) : 0.f;
      float2 f0 = *(const float2*)&F[(size_t)s0 * 128 + c0];
      float2 f1 = *(const float2*)&F[(size_t)s1 * 128 + c0];
      float2 f2 = *(const float2*)&F[(size_t)s2 * 128 + c0];
      float2 f3 = *(const float2*)&F[(size_t)s3 * 128 + c0];
      acc.x += w0 * f0.x + w1 * f1.x + w2 * f2.x + w3 * f3.x;
      acc.y += w0 * f0.y + w1 * f1.y + w2 * f2.y + w3 * f3.y;
    }
  } else {  // chunked wave path (degree > 64 — rare)
    float lm = -INFINITY;
    for (int t = lane; t < n; t += 64) {
      int sv = adj_src[beg + t];
      float v = el[sv] + er_d;
      v = v > 0.f ? v : 0.2f * v;
      lm = fmaxf(lm, v);
    }
#pragma unroll
    for (int off = 32; off; off >>= 1) lm = fmaxf(lm, __shfl_xor(lm, off));
    float ls = 0.f;
    for (int t = lane; t < n; t += 64) {
      int sv = adj_src[beg + t];
      float v = el[sv] + er_d;
      v = v > 0.f ? v : 0.2f * v;
      ls += expf(v - lm);
    }
#pragma unroll
    for (int off = 32; off; off >>= 1) ls += __shfl_xor(ls, off);
    for (int base = 0; base < n; base += 64) {
      int t = base + lane;
      int sv = 0; float wt = 0.f;
      if (t < n) {
        sv = adj_src[beg + t];
        float v = el[sv] + er_d;
        v = v > 0.f ? v : 0.2f * v;
        wt = expf(v - lm) / ls;
      }
      int cnt = min(64, n - base);
      for (int j = 0; j < cnt; ++j) {
        int s0 = __shfl(sv, j);
        float w0 = __shfl(wt, j);
        float2 f0 = *(const float2*)&F[(size_t)s0 * 128 + c0];
        acc.x += w0 * f0.x;
        acc.y += w0 * f0.y;
      }
    }
  }
  float2 o;
  o.x = fmaxf(acc.x + bv.x, 0.f);
  o.y = fmaxf(acc.y + bv.y, 0.f);
  *(float2*)&outX[(size_t)d * 128 + c0] = o;
}

// ---------------- atomic-path edge kernels (outer graph + fallback) ----------------
static __device__ __forceinline__ void atomicMaxF(float* addr, float v) {
  int iv = __float_as_int(v);
  if (iv >= 0) atomicMax((int*)addr, iv);
  else atomicMin((unsigned int*)addr, (unsigned int)iv);
}

static __device__ __forceinline__ float edge_score(const float* el, const float* er,
                                                   int sv, int dv) {
  float v = el[sv] + er[dv];
  return v > 0.f ? v : 0.2f * v;
}

__global__ void edge_max_kernel(const float* __restrict__ el,
                                const float* __restrict__ er,
                                const int* __restrict__ src,
                                const int* __restrict__ dst,
                                float* __restrict__ m, int nE) {
  int e = blockIdx.x * 256 + threadIdx.x;
  if (e >= nE) return;
  atomicMaxF(&m[dst[e]], edge_score(el, er, src[e], dst[e]));
}

__global__ void edge_expsum_kernel(const float* __restrict__ el,
                                   const float* __restrict__ er,
                                   const float* __restrict__ m,
                                   const int* __restrict__ src,
                                   const int* __restrict__ dst,
                                   float* __restrict__ s, int nE) {
  int e = blockIdx.x * 256 + threadIdx.x;
  if (e >= nE) return;
  int d = dst[e];
  atomicAdd(&s[d], expf(edge_score(el, er, src[e], d) - m[d]));
}

__global__ __launch_bounds__(128) void edge_aggregate_kernel(
    const float* __restrict__ f, const float* __restrict__ el,
    const float* __restrict__ er, const float* __restrict__ m,
    const float* __restrict__ s, const int* __restrict__ src,
    const int* __restrict__ dst, float* __restrict__ out, int nE) {
  int e = blockIdx.x;
  int d = threadIdx.x;
  int sv = src[e], dv = dst[e];
  float alpha = expf(edge_score(el, er, sv, dv) - m[dv]) / s[dv];
  atomicAdd(&out[(size_t)dv * 128 + d], alpha * f[(size_t)sv * 128 + d]);
}

__global__ void bias_relu_kernel(float* __restrict__ x,
                                 const float* __restrict__ b, int total) {
  int i = blockIdx.x * 256 + threadIdx.x;
  if (i >= total) return;
  x[i] = fmaxf(x[i] + b[i & 127], 0.f);
}

// ---------------- sort pooling ----------------
__global__ __launch_bounds__(64) void row_max_kernel(const float* __restrict__ x,
                                                     float* __restrict__ key) {
  int node = blockIdx.x, lane = threadIdx.x;
  float v = fmaxf(x[(size_t)node * 128 + lane], x[(size_t)node * 128 + 64 + lane]);
#pragma unroll
  for (int off = 32; off; off >>= 1) v = fmaxf(v, __shfl_down(v, off));
  if (lane == 0) key[node] = v;
}

__global__ __launch_bounds__(64) void select_topk_kernel(
    const float* __restrict__ key, int* __restrict__ sel) {
  __shared__ float keys[NPG];
  int g = blockIdx.x, t = threadIdx.x;
  keys[t] = key[(size_t)g * NPG + t];
  __syncthreads();
  float myk = keys[t];
  int rank = 0;
  for (int j = 0; j < NPG; ++j) {
    float kj = keys[j];
    rank += (kj > myk) || (kj == myk && j < t);
  }
  if (rank < KK) sel[g * KK + rank] = t;
}

__global__ __launch_bounds__(128) void sort_rows_kernel(
    const float* __restrict__ x, const int* __restrict__ sel,
    float* __restrict__ xp) {
  __shared__ float v[128];
  int b = blockIdx.x;
  int t = threadIdx.x;
  int g = b >> 3, r = b & 7;
  int node = sel[b];
  v[t] = x[(size_t)(g * NPG + node) * 128 + t];
  __syncthreads();
  for (int k = 2; k <= 128; k <<= 1) {
    for (int j = k >> 1; j > 0; j >>= 1) {
      int ixj = t ^ j;
      if (ixj > t) {
        float a = v[t], bb = v[ixj];
        bool asc = ((t & k) == 0);
        if (asc ? (a > bb) : (a < bb)) { v[t] = bb; v[ixj] = a; }
      }
      __syncthreads();
    }
  }
  xp[(size_t)g * (KK * 128) + r * 128 + t] = v[t];
}

// ---------------- classifier ----------------
__global__ __launch_bounds__(64) void classifier_kernel(
    const float* __restrict__ x, const float* __restrict__ Wc,
    const float* __restrict__ bc, float* __restrict__ out) {
  int g = blockIdx.x, lane = threadIdx.x;
  float v1 = x[(size_t)g * 128 + lane];
  float v2 = x[(size_t)g * 128 + 64 + lane];
  float a0 = v1 * Wc[lane * 2 + 0] + v2 * Wc[(64 + lane) * 2 + 0];
  float a1 = v1 * Wc[lane * 2 + 1] + v2 * Wc[(64 + lane) * 2 + 1];
#pragma unroll
  for (int off = 32; off; off >>= 1) {
    a0 += __shfl_down(a0, off);
    a1 += __shfl_down(a1, off);
  }
  if (lane == 0) {
    out[g * 2 + 0] = a0 + bc[0];
    out[g * 2 + 1] = a1 + bc[1];
  }
}

// ---------------- launcher ----------------
extern "C" void kernel_launch(void* const* d_in, const int* in_sizes, int n_in,
                              void* d_out, int out_size, void* d_ws, size_t ws_size,
                              hipStream_t stream) {
  const size_t BASE_FLOATS = (size_t)NN * DD * 2 + (size_t)NN * 4;  // X,F,el,er,mx,sm
  const size_t CSR_INTS = (size_t)(NN + 1) + NN + EE + 128;          // row_ptr,cursor,adj,part
  if (ws_size < BASE_FLOATS * sizeof(float)) {
    hipMemsetAsync(d_out, 0, (size_t)out_size * sizeof(float), stream);
    return;
  }
  const bool use_csr = ws_size >= BASE_FLOATS * sizeof(float) + CSR_INTS * sizeof(int);

  const int* h      = (const int*)d_in[0];
  const int* g_src  = (const int*)d_in[1];
  const int* g_dst  = (const int*)d_in[2];
  const int* fg_src = (const int*)d_in[3];
  const int* fg_dst = (const int*)d_in[4];
  const float* temb = (const float*)d_in[5];
  const float* W1 = (const float*)d_in[6];
  const float* al1 = (const float*)d_in[7];
  const float* ar1 = (const float*)d_in[8];
  const float* b1 = (const float*)d_in[9];
  const float* W2 = (const float*)d_in[10];
  const float* al2 = (const float*)d_in[11];
  const float* ar2 = (const float*)d_in[12];
  const float* b2 = (const float*)d_in[13];
  const float* W3 = (const float*)d_in[14];
  const float* al3 = (const float*)d_in[15];
  const float* ar3 = (const float*)d_in[16];
  const float* b3 = (const float*)d_in[17];
  const float* Wf = (const float*)d_in[18];
  const float* bfv = (const float*)d_in[19];
  const float* Wl = (const float*)d_in[20];
  const float* bl = (const float*)d_in[21];
  const float* Wl1 = (const float*)d_in[22];
  const float* bl1 = (const float*)d_in[23];
  const float* Wc = (const float*)d_in[24];
  const float* bc = (const float*)d_in[25];
  float* out = (float*)d_out;

  // ---- workspace layout ----
  float* ws = (float*)d_ws;
  float* X  = ws;
  float* F  = X + (size_t)NN * DD;
  float* el = F + (size_t)NN * DD;
  float* er = el + NN;
  float* mx = er + NN;
  float* sm = mx + NN;
  int* row_ptr = (int*)(sm + NN);
  int* cursor  = row_ptr + NN + 1;
  int* adj_src = cursor + NN;
  int* part    = adj_src + EE;
  // carved from F once F is dead (after layer-2 aggregation):
  float* xp   = F;
  float* f3   = F + 2097152;
  float* g3   = f3 + (size_t)GG * DD;
  float* t1   = g3 + (size_t)GG * DD;
  float* t2   = t1 + (size_t)GG * DD;
  float* keyb = t2 + (size_t)GG * DD;
  int*   sel  = (int*)(keyb + NN);

  const int totalND = NN * DD;

  if (use_csr) {
    // ---- build CSR of inner graph by dst (reused by both GAT layers) ----
    zero_int_kernel<<<NN / 256, 256, 0, stream>>>(cursor, NN);
    hist_kernel<<<EE / 256, 256, 0, stream>>>(g_dst, cursor, EE);
    scan_block_kernel<<<NN / 1024, 256, 0, stream>>>(cursor, row_ptr, part);
    scan_part_kernel<<<1, 128, 0, stream>>>(part);
    scan_add_kernel<<<(NN + 255) / 256, 256, 0, stream>>>(row_ptr, part, NN, EE);
    zero_int_kernel<<<NN / 256, 256, 0, stream>>>(cursor, NN);
    scatter_kernel<<<EE / 256, 256, 0, stream>>>(g_dst, g_src, row_ptr, cursor, adj_src, EE);

    // layer 1: F = relu(temb[h]) @ W1 fused with embed-gather + el/er epilogue
    gemm128_fused<1, 1><<<NN / 64, 256, 0, stream>>>(
        nullptr, temb, h, W1, nullptr, F, al1, ar1, el, er, nullptr);
    gat_aggregate_csr_kernel<<<NN / 4, 256, 0, stream>>>(F, el, er, row_ptr, adj_src, b1, X);

    // layer 2
    gemm128_fused<0, 1><<<NN / 64, 256, 0, stream>>>(
        X, nullptr, nullptr, W2, nullptr, F, al2, ar2, el, er, nullptr);
    gat_aggregate_csr_kernel<<<NN / 4, 256, 0, stream>>>(F, el, er, row_ptr, adj_src, b2, X);

    // linear_forward in-place + fused row-max
    gemm128_fused<0, 2><<<NN / 64, 256, 0, stream>>>(
        X, nullptr, nullptr, Wf, bfv, X, nullptr, nullptr, nullptr, nullptr, keyb);
  } else {
    embed_relu_kernel<<<totalND / 256, 256, 0, stream>>>(temb, h, X, totalND);
    auto gat_inner = [&](const float* W, const float* al, const float* ar, const float* bb) {
      gemm_kernel<DD, 8><<<NN / 8, 128, 0, stream>>>(X, W, nullptr, F, 0);
      attn_logits_kernel<<<NN, 64, 0, stream>>>(F, al, ar, el, er);
      init_softmax_kernel<<<(NN + 255) / 256, 256, 0, stream>>>(mx, sm, NN);
      fill_f32_kernel<<<totalND / 256, 256, 0, stream>>>(X, 0.f, totalND);
      edge_max_kernel<<<(EE + 255) / 256, 256, 0, stream>>>(el, er, g_src, g_dst, mx, EE);
      edge_expsum_kernel<<<(EE + 255) / 256, 256, 0, stream>>>(el, er, mx, g_src, g_dst, sm, EE);
      edge_aggregate_kernel<<<EE, 128, 0, stream>>>(F, el, er, mx, sm, g_src, g_dst, X, EE);
      bias_relu_kernel<<<totalND / 256, 256, 0, stream>>>(X, bb, totalND);
    };
    gat_inner(W1, al1, ar1, b1);
    gat_inner(W2, al2, ar2, b2);
    gemm_kernel<DD, 8><<<NN / 8, 128, 0, stream>>>(X, Wf, bfv, X, 1);
    row_max_kernel<<<NN, 64, 0, stream>>>(X, keyb);
  }

  // sort pooling -> xp [G, 1024]
  select_topk_kernel<<<GG, 64, 0, stream>>>(keyb, sel);
  sort_rows_kernel<<<GG * KK, 128, 0, stream>>>(X, sel, xp);

  // outer GAT over fg (atomic path — small)
  gemm_kernel<KK * DD, 8><<<GG / 8, 128, 0, stream>>>(xp, W3, nullptr, f3, 0);
  attn_logits_kernel<<<GG, 64, 0, stream>>>(f3, al3, ar3, el, er);
  init_softmax_kernel<<<(GG + 255) / 256, 256, 0, stream>>>(mx, sm, GG);
  fill_f32_kernel<<<(GG * DD + 255) / 256, 256, 0, stream>>>(g3, 0.f, GG * DD);
  edge_max_kernel<<<(EFN + 255) / 256, 256, 0, stream>>>(el, er, fg_src, fg_dst, mx, EFN);
  edge_expsum_kernel<<<(EFN + 255) / 256, 256, 0, stream>>>(el, er, mx, fg_src, fg_dst, sm, EFN);
  edge_aggregate_kernel<<<EFN, 128, 0, stream>>>(f3, el, er, mx, sm, fg_src, fg_dst, g3, EFN);
  bias_relu_kernel<<<(GG * DD + 255) / 256, 256, 0, stream>>>(g3, b3, GG * DD);

  // t1 = relu(g3 @ Wl + bl); t2 = relu(t1 @ Wl1 + bl1)
  gemm_kernel<DD, 8><<<GG / 8, 128, 0, stream>>>(g3, Wl, bl, t1, 1);
  gemm_kernel<DD, 8><<<GG / 8, 128, 0, stream>>>(t1, Wl1, bl1, t2, 1);

  // classifier -> fp32 out [G,2]
  classifier_kernel<<<GG, 64, 0, stream>>>(t2, Wc, bc, out);
}

// Round 12
// 724.927 us; speedup vs baseline: 4.0727x; 1.0714x over previous
//
#include <hip/hip_runtime.h>
#include <math.h>

#define NN   131072   // total inner nodes
#define GG   2048     // graphs
#define NPG  64       // nodes per graph
#define EE   1048576  // inner edges
#define EFN  32768    // outer edges
#define DD   128      // feature dim
#define KK   8        // sortpool k

// ---------------- utility ----------------
__global__ void fill_f32_kernel(float* __restrict__ p, float v, int nElems) {
  int i = blockIdx.x * 256 + threadIdx.x;
  if (i < nElems) p[i] = v;
}

__global__ void zero_int_kernel(int* __restrict__ p, int nElems) {
  int i = blockIdx.x * 256 + threadIdx.x;
  if (i < nElems) p[i] = 0;
}

__global__ void init_softmax_kernel(float* __restrict__ mx, float* __restrict__ sm, int nElems) {
  int i = blockIdx.x * 256 + threadIdx.x;
  if (i < nElems) { mx[i] = -INFINITY; sm[i] = 0.f; }
}

// x[i] = relu(token_emb[h[node]][d])   (fallback path only)
__global__ void embed_relu_kernel(const float* __restrict__ temb,
                                  const int* __restrict__ h,
                                  float* __restrict__ x, int total) {
  int i = blockIdx.x * 256 + threadIdx.x;
  if (i >= total) return;
  int node = i >> 7, d = i & 127;
  x[i] = fmaxf(temb[h[node] * DD + d], 0.f);
}

// ---------------- small / generic GEMM (outer graph, fallback) ----------------
template <int KD, int ROWS>
__global__ __launch_bounds__(128) void gemm_kernel(
    const float* __restrict__ A, const float* __restrict__ W,
    const float* __restrict__ bias, float* __restrict__ out,
    int relu_flag) {
  __shared__ float As[ROWS * KD];
  const int row0 = blockIdx.x * ROWS;
  const int tid = threadIdx.x;
  for (int i = tid; i < ROWS * KD; i += 128) As[i] = A[(size_t)row0 * KD + i];
  __syncthreads();
  float acc[ROWS];
#pragma unroll
  for (int r = 0; r < ROWS; r++) acc[r] = 0.f;
  for (int k = 0; k < KD; k++) {
    float w = W[k * 128 + tid];
#pragma unroll
    for (int r = 0; r < ROWS; r++) acc[r] += As[r * KD + k] * w;
  }
  float b = bias ? bias[tid] : 0.f;
#pragma unroll
  for (int r = 0; r < ROWS; r++) {
    float v = acc[r] + b;
    if (relu_flag) v = fmaxf(v, 0.f);
    out[(size_t)(row0 + r) * 128 + tid] = v;
  }
}

// ---------------- outer-GAT GEMM: f3[G,128] = xp[G,1024] @ W3[1024,128] ----------------
// 8 rows/block, 256 threads: thread = (col, K-half). K unrolled x4 (4 W loads
// feed 32 FMAs from float4 LDS reads), 8KB LDS cross-half reduction.
__global__ __launch_bounds__(256) void gemm1024_kernel(
    const float* __restrict__ A, const float* __restrict__ W,
    float* __restrict__ out) {
  __shared__ float As[8 * 1024];
  __shared__ float red[8][256];
  const int t = threadIdx.x;
  const int row0 = blockIdx.x * 8;
  for (int idx = t; idx < 8 * 256; idx += 256) {
    int r = idx >> 8, c4 = (idx & 255) << 2;
    *(float4*)&As[r * 1024 + c4] = *(const float4*)(A + (size_t)(row0 + r) * 1024 + c4);
  }
  __syncthreads();
  const int col = t & 127, kh = t >> 7;
  const int k0 = kh * 512;
  float acc[8];
#pragma unroll
  for (int r = 0; r < 8; r++) acc[r] = 0.f;
  for (int k = k0; k < k0 + 512; k += 4) {
    float w0 = W[(size_t)(k + 0) * 128 + col];
    float w1 = W[(size_t)(k + 1) * 128 + col];
    float w2 = W[(size_t)(k + 2) * 128 + col];
    float w3 = W[(size_t)(k + 3) * 128 + col];
#pragma unroll
    for (int r = 0; r < 8; r++) {
      float4 a = *(const float4*)&As[r * 1024 + k];
      acc[r] += a.x * w0 + a.y * w1 + a.z * w2 + a.w * w3;
    }
  }
#pragma unroll
  for (int r = 0; r < 8; r++) red[r][t] = acc[r];
  __syncthreads();
  for (int idx = t; idx < 1024; idx += 256) {
    int r = idx >> 7, c = idx & 127;
    out[(size_t)(row0 + r) * 128 + c] = red[r][c] + red[r][128 + c];
  }
}

// ---------------- fused tiled GEMM: out[M,128] = act(A)[M,128] @ W[128,128] ----------------
template <int SRC_MODE, int EPI>
__global__ __launch_bounds__(256) void gemm128_fused(
    const float* __restrict__ A, const float* __restrict__ temb,
    const int* __restrict__ hidx, const float* __restrict__ W,
    const float* __restrict__ bias, float* __restrict__ out,
    const float* __restrict__ al, const float* __restrict__ ar,
    float* __restrict__ el, float* __restrict__ er,
    float* __restrict__ keyb) {
  __shared__ float As[64 * 128];
  const int t = threadIdx.x;
  const int row0 = blockIdx.x * 64;
  for (int idx = t; idx < 64 * 32; idx += 256) {
    int r = idx >> 5, c4 = (idx & 31) << 2;
    if (SRC_MODE == 1) {
      const float* src = temb + (size_t)hidx[row0 + r] * 128 + c4;
      float4 v = *(const float4*)src;
      v.x = fmaxf(v.x, 0.f); v.y = fmaxf(v.y, 0.f);
      v.z = fmaxf(v.z, 0.f); v.w = fmaxf(v.w, 0.f);
      *(float4*)&As[r * 128 + c4] = v;
    } else {
      *(float4*)&As[r * 128 + c4] = *(const float4*)(A + (size_t)(row0 + r) * 128 + c4);
    }
  }
  __syncthreads();
  const int rg = t >> 5, cg = t & 31;
  const int r0 = rg * 8, c0 = cg * 4;
  float acc[8][4];
#pragma unroll
  for (int i = 0; i < 8; i++)
#pragma unroll
    for (int j = 0; j < 4; j++) acc[i][j] = 0.f;
  for (int k = 0; k < 128; k += 4) {
    float4 w0 = *(const float4*)(W + (size_t)(k + 0) * 128 + c0);
    float4 w1 = *(const float4*)(W + (size_t)(k + 1) * 128 + c0);
    float4 w2 = *(const float4*)(W + (size_t)(k + 2) * 128 + c0);
    float4 w3 = *(const float4*)(W + (size_t)(k + 3) * 128 + c0);
#pragma unroll
    for (int i = 0; i < 8; i++) {
      float4 a = *(const float4*)&As[(r0 + i) * 128 + k];
      acc[i][0] += a.x * w0.x + a.y * w1.x + a.z * w2.x + a.w * w3.x;
      acc[i][1] += a.x * w0.y + a.y * w1.y + a.z * w2.y + a.w * w3.y;
      acc[i][2] += a.x * w0.z + a.y * w1.z + a.z * w2.z + a.w * w3.z;
      acc[i][3] += a.x * w0.w + a.y * w1.w + a.z * w2.w + a.w * w3.w;
    }
  }
  if (EPI == 0) {
#pragma unroll
    for (int i = 0; i < 8; i++) {
      float4 v = make_float4(acc[i][0], acc[i][1], acc[i][2], acc[i][3]);
      *(float4*)(out + (size_t)(row0 + r0 + i) * 128 + c0) = v;
    }
  } else if (EPI == 1) {
    float4 alv = *(const float4*)(al + c0);
    float4 arv = *(const float4*)(ar + c0);
#pragma unroll
    for (int i = 0; i < 8; i++) {
      float4 v = make_float4(acc[i][0], acc[i][1], acc[i][2], acc[i][3]);
      *(float4*)(out + (size_t)(row0 + r0 + i) * 128 + c0) = v;
      float pl = v.x * alv.x + v.y * alv.y + v.z * alv.z + v.w * alv.w;
      float pr = v.x * arv.x + v.y * arv.y + v.z * arv.z + v.w * arv.w;
#pragma unroll
      for (int off = 16; off; off >>= 1) {
        pl += __shfl_down(pl, off, 32);
        pr += __shfl_down(pr, off, 32);
      }
      if (cg == 0) {
        el[row0 + r0 + i] = pl;
        er[row0 + r0 + i] = pr;
      }
    }
  } else {  // EPI == 2
    float4 bv = *(const float4*)(bias + c0);
#pragma unroll
    for (int i = 0; i < 8; i++) {
      float4 v;
      v.x = fmaxf(acc[i][0] + bv.x, 0.f);
      v.y = fmaxf(acc[i][1] + bv.y, 0.f);
      v.z = fmaxf(acc[i][2] + bv.z, 0.f);
      v.w = fmaxf(acc[i][3] + bv.w, 0.f);
      *(float4*)(out + (size_t)(row0 + r0 + i) * 128 + c0) = v;
      float pm = fmaxf(fmaxf(v.x, v.y), fmaxf(v.z, v.w));
#pragma unroll
      for (int off = 16; off; off >>= 1) pm = fmaxf(pm, __shfl_down(pm, off, 32));
      if (cg == 0) keyb[row0 + r0 + i] = pm;
    }
  }
}

// ---------------- attention logits (outer graph, fallback) ----------------
__global__ __launch_bounds__(64) void attn_logits_kernel(
    const float* __restrict__ f, const float* __restrict__ al,
    const float* __restrict__ ar, float* __restrict__ el,
    float* __restrict__ er) {
  int node = blockIdx.x, lane = threadIdx.x;
  float v1 = f[(size_t)node * 128 + lane];
  float v2 = f[(size_t)node * 128 + 64 + lane];
  float sl = v1 * al[lane] + v2 * al[64 + lane];
  float sr = v1 * ar[lane] + v2 * ar[64 + lane];
#pragma unroll
  for (int off = 32; off; off >>= 1) {
    sl += __shfl_down(sl, off);
    sr += __shfl_down(sr, off);
  }
  if (lane == 0) { el[node] = sl; er[node] = sr; }
}

// ---------------- CSR build ----------------
__global__ void hist_kernel(const int* __restrict__ dst, int* __restrict__ cnt, int nE) {
  int e = blockIdx.x * 256 + threadIdx.x;
  if (e < nE) atomicAdd(&cnt[dst[e]], 1);
}

__global__ __launch_bounds__(256) void scan_block_kernel(
    const int* __restrict__ cnt, int* __restrict__ excl, int* __restrict__ part) {
  __shared__ int s[256];
  int blk = blockIdx.x, tid = threadIdx.x;
  int base = blk * 1024 + tid * 4;
  int a0 = cnt[base], a1 = cnt[base + 1], a2 = cnt[base + 2], a3 = cnt[base + 3];
  int tsum = a0 + a1 + a2 + a3;
  s[tid] = tsum; __syncthreads();
  for (int off = 1; off < 256; off <<= 1) {
    int v = (tid >= off) ? s[tid - off] : 0;
    __syncthreads();
    s[tid] += v;
    __syncthreads();
  }
  int texcl = s[tid] - tsum;
  excl[base]     = texcl;
  excl[base + 1] = texcl + a0;
  excl[base + 2] = texcl + a0 + a1;
  excl[base + 3] = texcl + a0 + a1 + a2;
  if (tid == 255) part[blk] = s[255];
}

__global__ __launch_bounds__(128) void scan_part_kernel(int* __restrict__ part) {
  __shared__ int s[128];
  int tid = threadIdx.x;
  int orig = part[tid];
  s[tid] = orig; __syncthreads();
  for (int off = 1; off < 128; off <<= 1) {
    int v = (tid >= off) ? s[tid - off] : 0;
    __syncthreads();
    s[tid] += v;
    __syncthreads();
  }
  part[tid] = s[tid] - orig;
}

__global__ void scan_add_kernel(int* __restrict__ row_ptr, const int* __restrict__ part,
                                int n, int total) {
  int i = blockIdx.x * 256 + threadIdx.x;
  if (i < n) row_ptr[i] += part[i >> 10];
  if (i == 0) row_ptr[n] = total;
}

// store src node id directly in adjacency (kills the src[eidx[]] indirection)
__global__ void scatter_kernel(const int* __restrict__ dst, const int* __restrict__ src,
                               const int* __restrict__ row_ptr,
                               int* __restrict__ cursor, int* __restrict__ adj_src, int nE) {
  int e = blockIdx.x * 256 + threadIdx.x;
  if (e >= nE) return;
  int d = dst[e];
  int pos = row_ptr[d] + atomicAdd(&cursor[d], 1);
  adj_src[pos] = src[e];
}

// ---------------- fused CSR GAT aggregation: one 64-lane wave per dst ----------------
__global__ __launch_bounds__(256) void gat_aggregate_csr_kernel(
    const float* __restrict__ F, const float* __restrict__ el,
    const float* __restrict__ er, const int* __restrict__ row_ptr,
    const int* __restrict__ adj_src,
    const float* __restrict__ bias, float* __restrict__ outX) {
  const int lane = threadIdx.x & 63;
  const int d = blockIdx.x * 4 + (threadIdx.x >> 6);
  const int c0 = lane * 2;
  int beg = row_ptr[d];
  int n = row_ptr[d + 1] - beg;
  float2 bv = *(const float2*)&bias[c0];
  if (n == 0) {
    float2 o; o.x = fmaxf(bv.x, 0.f); o.y = fmaxf(bv.y, 0.f);
    *(float2*)&outX[(size_t)d * 128 + c0] = o;
    return;
  }
  float er_d = er[d];
  float2 acc = make_float2(0.f, 0.f);
  if (n <= 64) {  // fast path: avg degree 8
    int sv = 0; float sc = -INFINITY;
    if (lane < n) {
      sv = adj_src[beg + lane];
      float v = el[sv] + er_d;
      sc = v > 0.f ? v : 0.2f * v;
    }
    float m = sc;
#pragma unroll
    for (int off = 32; off; off >>= 1) m = fmaxf(m, __shfl_xor(m, off));
    float ex = (lane < n) ? expf(sc - m) : 0.f;
    float s = ex;
#pragma unroll
    for (int off = 32; off; off >>= 1) s += __shfl_xor(s, off);
    float wt = ex / s;
    for (int j = 0; j < n; j += 4) {
      int   s0 = __shfl(sv, j);
      float w0 = __shfl(wt, j);
      int   j1 = (j + 1 < n) ? j + 1 : j;
      int   s1 = __shfl(sv, j1); float w1 = (j + 1 < n) ? __shfl(wt, j1) : 0.f;
      int   j2 = (j + 2 < n) ? j + 2 : j;
      int   s2 = __shfl(sv, j2); float w2 = (j + 2 < n) ? __shfl(wt, j2) : 0.f;
      int   j3 = (j + 3 < n) ? j + 3 : j;
      int   s3 = __shfl(sv, j3); float w3 = (j + 3 < n) ? __shfl(wt, j3) : 0.f;
      float2 f0 = *(const float2*)&F[(size_t)s0 * 128 + c0];
      float2 f1 = *(const float2*)&F[(size_t)s1 * 128 + c0];
      float2 f2 = *(const float2*)&F[(size_t)s2 * 128 + c0];
      float2 f3 = *(const float2*)&F[(size_t)s3 * 128 + c0];
      acc.x += w0 * f0.x + w1 * f1.x + w2 * f2.x + w3 * f3.x;
      acc.y += w0 * f0.y + w1 * f1.y + w2 * f2.y + w3 * f3.y;
    }
  } else {  // chunked wave path (degree > 64 — rare)
    float lm = -INFINITY;
    for (int t = lane; t < n; t += 64) {
      int sv = adj_src[beg + t];
      float v = el[sv] + er_d;
      v = v > 0.f ? v : 0.2f * v;
      lm = fmaxf(lm, v);
    }
#pragma unroll
    for (int off = 32; off; off >>= 1) lm = fmaxf(lm, __shfl_xor(lm, off));
    float ls = 0.f;
    for (int t = lane; t < n; t += 64) {
      int sv = adj_src[beg + t];
      float v = el[sv] + er_d;
      v = v > 0.f ? v : 0.2f * v;
      ls += expf(v - lm);
    }
#pragma unroll
    for (int off = 32; off; off >>= 1) ls += __shfl_xor(ls, off);
    for (int base = 0; base < n; base += 64) {
      int t = base + lane;
      int sv = 0; float wt = 0.f;
      if (t < n) {
        sv = adj_src[beg + t];
        float v = el[sv] + er_d;
        v = v > 0.f ? v : 0.2f * v;
        wt = expf(v - lm) / ls;
      }
      int cnt = min(64, n - base);
      for (int j = 0; j < cnt; ++j) {
        int s0 = __shfl(sv, j);
        float w0 = __shfl(wt, j);
        float2 f0 = *(const float2*)&F[(size_t)s0 * 128 + c0];
        acc.x += w0 * f0.x;
        acc.y += w0 * f0.y;
      }
    }
  }
  float2 o;
  o.x = fmaxf(acc.x + bv.x, 0.f);
  o.y = fmaxf(acc.y + bv.y, 0.f);
  *(float2*)&outX[(size_t)d * 128 + c0] = o;
}

// ---------------- atomic-path edge kernels (outer graph + fallback) ----------------
static __device__ __forceinline__ void atomicMaxF(float* addr, float v) {
  int iv = __float_as_int(v);
  if (iv >= 0) atomicMax((int*)addr, iv);
  else atomicMin((unsigned int*)addr, (unsigned int)iv);
}

static __device__ __forceinline__ float edge_score(const float* el, const float* er,
                                                   int sv, int dv) {
  float v = el[sv] + er[dv];
  return v > 0.f ? v : 0.2f * v;
}

__global__ void edge_max_kernel(const float* __restrict__ el,
                                const float* __restrict__ er,
                                const int* __restrict__ src,
                                const int* __restrict__ dst,
                                float* __restrict__ m, int nE) {
  int e = blockIdx.x * 256 + threadIdx.x;
  if (e >= nE) return;
  atomicMaxF(&m[dst[e]], edge_score(el, er, src[e], dst[e]));
}

__global__ void edge_expsum_kernel(const float* __restrict__ el,
                                   const float* __restrict__ er,
                                   const float* __restrict__ m,
                                   const int* __restrict__ src,
                                   const int* __restrict__ dst,
                                   float* __restrict__ s, int nE) {
  int e = blockIdx.x * 256 + threadIdx.x;
  if (e >= nE) return;
  int d = dst[e];
  atomicAdd(&s[d], expf(edge_score(el, er, src[e], d) - m[d]));
}

__global__ __launch_bounds__(128) void edge_aggregate_kernel(
    const float* __restrict__ f, const float* __restrict__ el,
    const float* __restrict__ er, const float* __restrict__ m,
    const float* __restrict__ s, const int* __restrict__ src,
    const int* __restrict__ dst, float* __restrict__ out, int nE) {
  int e = blockIdx.x;
  int d = threadIdx.x;
  int sv = src[e], dv = dst[e];
  float alpha = expf(edge_score(el, er, sv, dv) - m[dv]) / s[dv];
  atomicAdd(&out[(size_t)dv * 128 + d], alpha * f[(size_t)sv * 128 + d]);
}

__global__ void bias_relu_kernel(float* __restrict__ x,
                                 const float* __restrict__ b, int total) {
  int i = blockIdx.x * 256 + threadIdx.x;
  if (i >= total) return;
  x[i] = fmaxf(x[i] + b[i & 127], 0.f);
}

// ---------------- sort pooling ----------------
__global__ __launch_bounds__(64) void row_max_kernel(const float* __restrict__ x,
                                                     float* __restrict__ key) {
  int node = blockIdx.x, lane = threadIdx.x;
  float v = fmaxf(x[(size_t)node * 128 + lane], x[(size_t)node * 128 + 64 + lane]);
#pragma unroll
  for (int off = 32; off; off >>= 1) v = fmaxf(v, __shfl_down(v, off));
  if (lane == 0) key[node] = v;
}

__global__ __launch_bounds__(64) void select_topk_kernel(
    const float* __restrict__ key, int* __restrict__ sel) {
  __shared__ float keys[NPG];
  int g = blockIdx.x, t = threadIdx.x;
  keys[t] = key[(size_t)g * NPG + t];
  __syncthreads();
  float myk = keys[t];
  int rank = 0;
  for (int j = 0; j < NPG; ++j) {
    float kj = keys[j];
    rank += (kj > myk) || (kj == myk && j < t);
  }
  if (rank < KK) sel[g * KK + rank] = t;
}

__global__ __launch_bounds__(128) void sort_rows_kernel(
    const float* __restrict__ x, const int* __restrict__ sel,
    float* __restrict__ xp) {
  __shared__ float v[128];
  int b = blockIdx.x;
  int t = threadIdx.x;
  int g = b >> 3, r = b & 7;
  int node = sel[b];
  v[t] = x[(size_t)(g * NPG + node) * 128 + t];
  __syncthreads();
  for (int k = 2; k <= 128; k <<= 1) {
    for (int j = k >> 1; j > 0; j >>= 1) {
      int ixj = t ^ j;
      if (ixj > t) {
        float a = v[t], bb = v[ixj];
        bool asc = ((t & k) == 0);
        if (asc ? (a > bb) : (a < bb)) { v[t] = bb; v[ixj] = a; }
      }
      __syncthreads();
    }
  }
  xp[(size_t)g * (KK * 128) + r * 128 + t] = v[t];
}

// ---------------- classifier ----------------
__global__ __launch_bounds__(64) void classifier_kernel(
    const float* __restrict__ x, const float* __restrict__ Wc,
    const float* __restrict__ bc, float* __restrict__ out) {
  int g = blockIdx.x, lane = threadIdx.x;
  float v1 = x[(size_t)g * 128 + lane];
  float v2 = x[(size_t)g * 128 + 64 + lane];
  float a0 = v1 * Wc[lane * 2 + 0] + v2 * Wc[(64 + lane) * 2 + 0];
  float a1 = v1 * Wc[lane * 2 + 1] + v2 * Wc[(64 + lane) * 2 + 1];
#pragma unroll
  for (int off = 32; off; off >>= 1) {
    a0 += __shfl_down(a0, off);
    a1 += __shfl_down(a1, off);
  }
  if (lane == 0) {
    out[g * 2 + 0] = a0 + bc[0];
    out[g * 2 + 1] = a1 + bc[1];
  }
}

// ---------------- launcher ----------------
extern "C" void kernel_launch(void* const* d_in, const int* in_sizes, int n_in,
                              void* d_out, int out_size, void* d_ws, size_t ws_size,
                              hipStream_t stream) {
  const size_t BASE_FLOATS = (size_t)NN * DD * 2 + (size_t)NN * 4;  // X,F,el,er,mx,sm
  const size_t CSR_INTS = (size_t)(NN + 1) + NN + EE + 128;          // row_ptr,cursor,adj,part
  if (ws_size < BASE_FLOATS * sizeof(float)) {
    hipMemsetAsync(d_out, 0, (size_t)out_size * sizeof(float), stream);
    return;
  }
  const bool use_csr = ws_size >= BASE_FLOATS * sizeof(float) + CSR_INTS * sizeof(int);

  const int* h      = (const int*)d_in[0];
  const int* g_src  = (const int*)d_in[1];
  const int* g_dst  = (const int*)d_in[2];
  const int* fg_src = (const int*)d_in[3];
  const int* fg_dst = (const int*)d_in[4];
  const float* temb = (const float*)d_in[5];
  const float* W1 = (const float*)d_in[6];
  const float* al1 = (const float*)d_in[7];
  const float* ar1 = (const float*)d_in[8];
  const float* b1 = (const float*)d_in[9];
  const float* W2 = (const float*)d_in[10];
  const float* al2 = (const float*)d_in[11];
  const float* ar2 = (const float*)d_in[12];
  const float* b2 = (const float*)d_in[13];
  const float* W3 = (const float*)d_in[14];
  const float* al3 = (const float*)d_in[15];
  const float* ar3 = (const float*)d_in[16];
  const float* b3 = (const float*)d_in[17];
  const float* Wf = (const float*)d_in[18];
  const float* bfv = (const float*)d_in[19];
  const float* Wl = (const float*)d_in[20];
  const float* bl = (const float*)d_in[21];
  const float* Wl1 = (const float*)d_in[22];
  const float* bl1 = (const float*)d_in[23];
  const float* Wc = (const float*)d_in[24];
  const float* bc = (const float*)d_in[25];
  float* out = (float*)d_out;

  // ---- workspace layout ----
  float* ws = (float*)d_ws;
  float* X  = ws;
  float* F  = X + (size_t)NN * DD;
  float* el = F + (size_t)NN * DD;
  float* er = el + NN;
  float* mx = er + NN;
  float* sm = mx + NN;
  int* row_ptr = (int*)(sm + NN);
  int* cursor  = row_ptr + NN + 1;
  int* adj_src = cursor + NN;
  int* part    = adj_src + EE;
  // carved from F once F is dead (after layer-2 aggregation):
  float* xp   = F;
  float* f3   = F + 2097152;
  float* g3   = f3 + (size_t)GG * DD;
  float* t1   = g3 + (size_t)GG * DD;
  float* t2   = t1 + (size_t)GG * DD;
  float* keyb = t2 + (size_t)GG * DD;
  int*   sel  = (int*)(keyb + NN);

  const int totalND = NN * DD;

  if (use_csr) {
    // ---- build CSR of inner graph by dst (reused by both GAT layers) ----
    zero_int_kernel<<<NN / 256, 256, 0, stream>>>(cursor, NN);
    hist_kernel<<<EE / 256, 256, 0, stream>>>(g_dst, cursor, EE);
    scan_block_kernel<<<NN / 1024, 256, 0, stream>>>(cursor, row_ptr, part);
    scan_part_kernel<<<1, 128, 0, stream>>>(part);
    scan_add_kernel<<<(NN + 255) / 256, 256, 0, stream>>>(row_ptr, part, NN, EE);
    zero_int_kernel<<<NN / 256, 256, 0, stream>>>(cursor, NN);
    scatter_kernel<<<EE / 256, 256, 0, stream>>>(g_dst, g_src, row_ptr, cursor, adj_src, EE);

    // layer 1: F = relu(temb[h]) @ W1 fused with embed-gather + el/er epilogue
    gemm128_fused<1, 1><<<NN / 64, 256, 0, stream>>>(
        nullptr, temb, h, W1, nullptr, F, al1, ar1, el, er, nullptr);
    gat_aggregate_csr_kernel<<<NN / 4, 256, 0, stream>>>(F, el, er, row_ptr, adj_src, b1, X);

    // layer 2
    gemm128_fused<0, 1><<<NN / 64, 256, 0, stream>>>(
        X, nullptr, nullptr, W2, nullptr, F, al2, ar2, el, er, nullptr);
    gat_aggregate_csr_kernel<<<NN / 4, 256, 0, stream>>>(F, el, er, row_ptr, adj_src, b2, X);

    // linear_forward in-place + fused row-max
    gemm128_fused<0, 2><<<NN / 64, 256, 0, stream>>>(
        X, nullptr, nullptr, Wf, bfv, X, nullptr, nullptr, nullptr, nullptr, keyb);
  } else {
    embed_relu_kernel<<<totalND / 256, 256, 0, stream>>>(temb, h, X, totalND);
    auto gat_inner = [&](const float* W, const float* al, const float* ar, const float* bb) {
      gemm_kernel<DD, 8><<<NN / 8, 128, 0, stream>>>(X, W, nullptr, F, 0);
      attn_logits_kernel<<<NN, 64, 0, stream>>>(F, al, ar, el, er);
      init_softmax_kernel<<<(NN + 255) / 256, 256, 0, stream>>>(mx, sm, NN);
      fill_f32_kernel<<<totalND / 256, 256, 0, stream>>>(X, 0.f, totalND);
      edge_max_kernel<<<(EE + 255) / 256, 256, 0, stream>>>(el, er, g_src, g_dst, mx, EE);
      edge_expsum_kernel<<<(EE + 255) / 256, 256, 0, stream>>>(el, er, mx, g_src, g_dst, sm, EE);
      edge_aggregate_kernel<<<EE, 128, 0, stream>>>(F, el, er, mx, sm, g_src, g_dst, X, EE);
      bias_relu_kernel<<<totalND / 256, 256, 0, stream>>>(X, bb, totalND);
    };
    gat_inner(W1, al1, ar1, b1);
    gat_inner(W2, al2, ar2, b2);
    gemm_kernel<DD, 8><<<NN / 8, 128, 0, stream>>>(X, Wf, bfv, X, 1);
    row_max_kernel<<<NN, 64, 0, stream>>>(X, keyb);
  }

  // sort pooling -> xp [G, 1024]
  select_topk_kernel<<<GG, 64, 0, stream>>>(keyb, sel);
  sort_rows_kernel<<<GG * KK, 128, 0, stream>>>(X, sel, xp);

  // outer GAT over fg (atomic path — small)
  gemm1024_kernel<<<GG / 8, 256, 0, stream>>>(xp, W3, f3);
  attn_logits_kernel<<<GG, 64, 0, stream>>>(f3, al3, ar3, el, er);
  init_softmax_kernel<<<(GG + 255) / 256, 256, 0, stream>>>(mx, sm, GG);
  fill_f32_kernel<<<(GG * DD + 255) / 256, 256, 0, stream>>>(g3, 0.f, GG * DD);
  edge_max_kernel<<<(EFN + 255) / 256, 256, 0, stream>>>(el, er, fg_src, fg_dst, mx, EFN);
  edge_expsum_kernel<<<(EFN + 255) / 256, 256, 0, stream>>>(el, er, mx, fg_src, fg_dst, sm, EFN);
  edge_aggregate_kernel<<<EFN, 128, 0, stream>>>(f3, el, er, mx, sm, fg_src, fg_dst, g3, EFN);
  bias_relu_kernel<<<(GG * DD + 255) / 256, 256, 0, stream>>>(g3, b3, GG * DD);

  // t1 = relu(g3 @ Wl + bl); t2 = relu(t1 @ Wl1 + bl1)
  gemm_kernel<DD, 8><<<GG / 8, 128, 0, stream>>>(g3, Wl, bl, t1, 1);
  gemm_kernel<DD, 8><<<GG / 8, 128, 0, stream>>>(t1, Wl1, bl1, t2, 1);

  // classifier -> fp32 out [G,2]
  classifier_kernel<<<GG, 64, 0, stream>>>(t2, Wc, bc, out);
}

// Round 13
// 666.751 us; speedup vs baseline: 4.4281x; 1.0873x over previous
//
#include <hip/hip_runtime.h>
#include <math.h>

#define NN   131072   // total inner nodes
#define GG   2048     // graphs
#define NPG  64       // nodes per graph
#define EE   1048576  // inner edges
#define EFN  32768    // outer edges
#define DD   128      // feature dim
#define KK   8        // sortpool k

typedef unsigned short bfu;  // raw bf16 bits

static __device__ __forceinline__ bfu f2b(float f) {  // RNE f32 -> bf16
  unsigned u = __float_as_uint(f);
  u += 0x7FFFu + ((u >> 16) & 1u);
  return (bfu)(u >> 16);
}
static __device__ __forceinline__ float b2f(bfu b) {
  return __uint_as_float(((unsigned)b) << 16);
}

// ---------------- utility ----------------
__global__ void fill_f32_kernel(float* __restrict__ p, float v, int nElems) {
  int i = blockIdx.x * 256 + threadIdx.x;
  if (i < nElems) p[i] = v;
}

__global__ void zero_int_kernel(int* __restrict__ p, int nElems) {
  int i = blockIdx.x * 256 + threadIdx.x;
  if (i < nElems) p[i] = 0;
}

__global__ void init_softmax_kernel(float* __restrict__ mx, float* __restrict__ sm, int nElems) {
  int i = blockIdx.x * 256 + threadIdx.x;
  if (i < nElems) { mx[i] = -INFINITY; sm[i] = 0.f; }
}

// x[i] = relu(token_emb[h[node]][d])   (fallback path only)
__global__ void embed_relu_kernel(const float* __restrict__ temb,
                                  const int* __restrict__ h,
                                  float* __restrict__ x, int total) {
  int i = blockIdx.x * 256 + threadIdx.x;
  if (i >= total) return;
  int node = i >> 7, d = i & 127;
  x[i] = fmaxf(temb[h[node] * DD + d], 0.f);
}

// ---------------- small / generic GEMM (outer graph, fallback) ----------------
template <int KD, int ROWS>
__global__ __launch_bounds__(128) void gemm_kernel(
    const float* __restrict__ A, const float* __restrict__ W,
    const float* __restrict__ bias, float* __restrict__ out,
    int relu_flag) {
  __shared__ float As[ROWS * KD];
  const int row0 = blockIdx.x * ROWS;
  const int tid = threadIdx.x;
  for (int i = tid; i < ROWS * KD; i += 128) As[i] = A[(size_t)row0 * KD + i];
  __syncthreads();
  float acc[ROWS];
#pragma unroll
  for (int r = 0; r < ROWS; r++) acc[r] = 0.f;
  for (int k = 0; k < KD; k++) {
    float w = W[k * 128 + tid];
#pragma unroll
    for (int r = 0; r < ROWS; r++) acc[r] += As[r * KD + k] * w;
  }
  float b = bias ? bias[tid] : 0.f;
#pragma unroll
  for (int r = 0; r < ROWS; r++) {
    float v = acc[r] + b;
    if (relu_flag) v = fmaxf(v, 0.f);
    out[(size_t)(row0 + r) * 128 + tid] = v;
  }
}

// ---------------- outer-GAT GEMM: f3[G,128] = xp[G,1024] @ W3[1024,128] ----------------
__global__ __launch_bounds__(256) void gemm1024_kernel(
    const float* __restrict__ A, const float* __restrict__ W,
    float* __restrict__ out) {
  __shared__ float As[8 * 1024];
  __shared__ float red[8][256];
  const int t = threadIdx.x;
  const int row0 = blockIdx.x * 8;
  for (int idx = t; idx < 8 * 256; idx += 256) {
    int r = idx >> 8, c4 = (idx & 255) << 2;
    *(float4*)&As[r * 1024 + c4] = *(const float4*)(A + (size_t)(row0 + r) * 1024 + c4);
  }
  __syncthreads();
  const int col = t & 127, kh = t >> 7;
  const int k0 = kh * 512;
  float acc[8];
#pragma unroll
  for (int r = 0; r < 8; r++) acc[r] = 0.f;
  for (int k = k0; k < k0 + 512; k += 4) {
    float w0 = W[(size_t)(k + 0) * 128 + col];
    float w1 = W[(size_t)(k + 1) * 128 + col];
    float w2 = W[(size_t)(k + 2) * 128 + col];
    float w3 = W[(size_t)(k + 3) * 128 + col];
#pragma unroll
    for (int r = 0; r < 8; r++) {
      float4 a = *(const float4*)&As[r * 1024 + k];
      acc[r] += a.x * w0 + a.y * w1 + a.z * w2 + a.w * w3;
    }
  }
#pragma unroll
  for (int r = 0; r < 8; r++) red[r][t] = acc[r];
  __syncthreads();
  for (int idx = t; idx < 1024; idx += 256) {
    int r = idx >> 7, c = idx & 127;
    out[(size_t)(row0 + r) * 128 + c] = red[r][c] + red[r][128 + c];
  }
}

// ---------------- fused tiled GEMM: out[M,128] = act(A)[M,128] @ W[128,128] ----------------
// EPI 1 stores OUT in bf16 (for the aggregate's gather) + fp32 el/er from
// full-precision accumulators. EPI 0/2 store fp32.
template <int SRC_MODE, int EPI>
__global__ __launch_bounds__(256) void gemm128_fused(
    const float* __restrict__ A, const float* __restrict__ temb,
    const int* __restrict__ hidx, const float* __restrict__ W,
    const float* __restrict__ bias, void* __restrict__ out,
    const float* __restrict__ al, const float* __restrict__ ar,
    float* __restrict__ el, float* __restrict__ er,
    float* __restrict__ keyb) {
  __shared__ float As[64 * 128];
  const int t = threadIdx.x;
  const int row0 = blockIdx.x * 64;
  for (int idx = t; idx < 64 * 32; idx += 256) {
    int r = idx >> 5, c4 = (idx & 31) << 2;
    if (SRC_MODE == 1) {
      const float* src = temb + (size_t)hidx[row0 + r] * 128 + c4;
      float4 v = *(const float4*)src;
      v.x = fmaxf(v.x, 0.f); v.y = fmaxf(v.y, 0.f);
      v.z = fmaxf(v.z, 0.f); v.w = fmaxf(v.w, 0.f);
      *(float4*)&As[r * 128 + c4] = v;
    } else {
      *(float4*)&As[r * 128 + c4] = *(const float4*)((const float*)A + (size_t)(row0 + r) * 128 + c4);
    }
  }
  __syncthreads();
  const int rg = t >> 5, cg = t & 31;
  const int r0 = rg * 8, c0 = cg * 4;
  float acc[8][4];
#pragma unroll
  for (int i = 0; i < 8; i++)
#pragma unroll
    for (int j = 0; j < 4; j++) acc[i][j] = 0.f;
  for (int k = 0; k < 128; k += 4) {
    float4 w0 = *(const float4*)(W + (size_t)(k + 0) * 128 + c0);
    float4 w1 = *(const float4*)(W + (size_t)(k + 1) * 128 + c0);
    float4 w2 = *(const float4*)(W + (size_t)(k + 2) * 128 + c0);
    float4 w3 = *(const float4*)(W + (size_t)(k + 3) * 128 + c0);
#pragma unroll
    for (int i = 0; i < 8; i++) {
      float4 a = *(const float4*)&As[(r0 + i) * 128 + k];
      acc[i][0] += a.x * w0.x + a.y * w1.x + a.z * w2.x + a.w * w3.x;
      acc[i][1] += a.x * w0.y + a.y * w1.y + a.z * w2.y + a.w * w3.y;
      acc[i][2] += a.x * w0.z + a.y * w1.z + a.z * w2.z + a.w * w3.z;
      acc[i][3] += a.x * w0.w + a.y * w1.w + a.z * w2.w + a.w * w3.w;
    }
  }
  if (EPI == 0) {
#pragma unroll
    for (int i = 0; i < 8; i++) {
      float4 v = make_float4(acc[i][0], acc[i][1], acc[i][2], acc[i][3]);
      *(float4*)((float*)out + (size_t)(row0 + r0 + i) * 128 + c0) = v;
    }
  } else if (EPI == 1) {
    float4 alv = *(const float4*)(al + c0);
    float4 arv = *(const float4*)(ar + c0);
#pragma unroll
    for (int i = 0; i < 8; i++) {
      ushort4 sv4;
      sv4.x = f2b(acc[i][0]); sv4.y = f2b(acc[i][1]);
      sv4.z = f2b(acc[i][2]); sv4.w = f2b(acc[i][3]);
      *(ushort4*)((bfu*)out + (size_t)(row0 + r0 + i) * 128 + c0) = sv4;
      float pl = acc[i][0] * alv.x + acc[i][1] * alv.y + acc[i][2] * alv.z + acc[i][3] * alv.w;
      float pr = acc[i][0] * arv.x + acc[i][1] * arv.y + acc[i][2] * arv.z + acc[i][3] * arv.w;
#pragma unroll
      for (int off = 16; off; off >>= 1) {
        pl += __shfl_down(pl, off, 32);
        pr += __shfl_down(pr, off, 32);
      }
      if (cg == 0) {
        el[row0 + r0 + i] = pl;
        er[row0 + r0 + i] = pr;
      }
    }
  } else {  // EPI == 2
    float4 bv = *(const float4*)(bias + c0);
#pragma unroll
    for (int i = 0; i < 8; i++) {
      float4 v;
      v.x = fmaxf(acc[i][0] + bv.x, 0.f);
      v.y = fmaxf(acc[i][1] + bv.y, 0.f);
      v.z = fmaxf(acc[i][2] + bv.z, 0.f);
      v.w = fmaxf(acc[i][3] + bv.w, 0.f);
      *(float4*)((float*)out + (size_t)(row0 + r0 + i) * 128 + c0) = v;
      float pm = fmaxf(fmaxf(v.x, v.y), fmaxf(v.z, v.w));
#pragma unroll
      for (int off = 16; off; off >>= 1) pm = fmaxf(pm, __shfl_down(pm, off, 32));
      if (cg == 0) keyb[row0 + r0 + i] = pm;
    }
  }
}

// ---------------- attention logits (outer graph, fallback) ----------------
__global__ __launch_bounds__(64) void attn_logits_kernel(
    const float* __restrict__ f, const float* __restrict__ al,
    const float* __restrict__ ar, float* __restrict__ el,
    float* __restrict__ er) {
  int node = blockIdx.x, lane = threadIdx.x;
  float v1 = f[(size_t)node * 128 + lane];
  float v2 = f[(size_t)node * 128 + 64 + lane];
  float sl = v1 * al[lane] + v2 * al[64 + lane];
  float sr = v1 * ar[lane] + v2 * ar[64 + lane];
#pragma unroll
  for (int off = 32; off; off >>= 1) {
    sl += __shfl_down(sl, off);
    sr += __shfl_down(sr, off);
  }
  if (lane == 0) { el[node] = sl; er[node] = sr; }
}

// ---------------- CSR build ----------------
__global__ void hist_kernel(const int* __restrict__ dst, int* __restrict__ cnt, int nE) {
  int e = blockIdx.x * 256 + threadIdx.x;
  if (e < nE) atomicAdd(&cnt[dst[e]], 1);
}

__global__ __launch_bounds__(256) void scan_block_kernel(
    const int* __restrict__ cnt, int* __restrict__ excl, int* __restrict__ part) {
  __shared__ int s[256];
  int blk = blockIdx.x, tid = threadIdx.x;
  int base = blk * 1024 + tid * 4;
  int a0 = cnt[base], a1 = cnt[base + 1], a2 = cnt[base + 2], a3 = cnt[base + 3];
  int tsum = a0 + a1 + a2 + a3;
  s[tid] = tsum; __syncthreads();
  for (int off = 1; off < 256; off <<= 1) {
    int v = (tid >= off) ? s[tid - off] : 0;
    __syncthreads();
    s[tid] += v;
    __syncthreads();
  }
  int texcl = s[tid] - tsum;
  excl[base]     = texcl;
  excl[base + 1] = texcl + a0;
  excl[base + 2] = texcl + a0 + a1;
  excl[base + 3] = texcl + a0 + a1 + a2;
  if (tid == 255) part[blk] = s[255];
}

__global__ __launch_bounds__(128) void scan_part_kernel(int* __restrict__ part) {
  __shared__ int s[128];
  int tid = threadIdx.x;
  int orig = part[tid];
  s[tid] = orig; __syncthreads();
  for (int off = 1; off < 128; off <<= 1) {
    int v = (tid >= off) ? s[tid - off] : 0;
    __syncthreads();
    s[tid] += v;
    __syncthreads();
  }
  part[tid] = s[tid] - orig;
}

__global__ void scan_add_kernel(int* __restrict__ row_ptr, const int* __restrict__ part,
                                int n, int total) {
  int i = blockIdx.x * 256 + threadIdx.x;
  if (i < n) row_ptr[i] += part[i >> 10];
  if (i == 0) row_ptr[n] = total;
}

__global__ void scatter_kernel(const int* __restrict__ dst, const int* __restrict__ src,
                               const int* __restrict__ row_ptr,
                               int* __restrict__ cursor, int* __restrict__ adj_src, int nE) {
  int e = blockIdx.x * 256 + threadIdx.x;
  if (e >= nE) return;
  int d = dst[e];
  int pos = row_ptr[d] + atomicAdd(&cursor[d], 1);
  adj_src[pos] = src[e];
}

// ---------------- fused CSR GAT aggregation: one 64-lane wave per dst ----------------
// F is bf16 (halves gather bytes); weights from fp32 el/er.
__global__ __launch_bounds__(256) void gat_aggregate_csr_kernel(
    const bfu* __restrict__ F, const float* __restrict__ el,
    const float* __restrict__ er, const int* __restrict__ row_ptr,
    const int* __restrict__ adj_src,
    const float* __restrict__ bias, float* __restrict__ outX) {
  const int lane = threadIdx.x & 63;
  const int d = blockIdx.x * 4 + (threadIdx.x >> 6);
  const int c0 = lane * 2;
  int beg = row_ptr[d];
  int n = row_ptr[d + 1] - beg;
  float2 bv = *(const float2*)&bias[c0];
  if (n == 0) {
    float2 o; o.x = fmaxf(bv.x, 0.f); o.y = fmaxf(bv.y, 0.f);
    *(float2*)&outX[(size_t)d * 128 + c0] = o;
    return;
  }
  float er_d = er[d];
  float2 acc = make_float2(0.f, 0.f);
  if (n <= 64) {  // fast path: avg degree 8
    int sv = 0; float sc = -INFINITY;
    if (lane < n) {
      sv = adj_src[beg + lane];
      float v = el[sv] + er_d;
      sc = v > 0.f ? v : 0.2f * v;
    }
    float m = sc;
#pragma unroll
    for (int off = 32; off; off >>= 1) m = fmaxf(m, __shfl_xor(m, off));
    float ex = (lane < n) ? expf(sc - m) : 0.f;
    float s = ex;
#pragma unroll
    for (int off = 32; off; off >>= 1) s += __shfl_xor(s, off);
    float wt = ex / s;
    for (int j = 0; j < n; j += 4) {
      int   s0 = __shfl(sv, j);
      float w0 = __shfl(wt, j);
      int   j1 = (j + 1 < n) ? j + 1 : j;
      int   s1 = __shfl(sv, j1); float w1 = (j + 1 < n) ? __shfl(wt, j1) : 0.f;
      int   j2 = (j + 2 < n) ? j + 2 : j;
      int   s2 = __shfl(sv, j2); float w2 = (j + 2 < n) ? __shfl(wt, j2) : 0.f;
      int   j3 = (j + 3 < n) ? j + 3 : j;
      int   s3 = __shfl(sv, j3); float w3 = (j + 3 < n) ? __shfl(wt, j3) : 0.f;
      ushort2 f0 = *(const ushort2*)&F[(size_t)s0 * 128 + c0];
      ushort2 f1 = *(const ushort2*)&F[(size_t)s1 * 128 + c0];
      ushort2 f2 = *(const ushort2*)&F[(size_t)s2 * 128 + c0];
      ushort2 f3 = *(const ushort2*)&F[(size_t)s3 * 128 + c0];
      acc.x += w0 * b2f(f0.x) + w1 * b2f(f1.x) + w2 * b2f(f2.x) + w3 * b2f(f3.x);
      acc.y += w0 * b2f(f0.y) + w1 * b2f(f1.y) + w2 * b2f(f2.y) + w3 * b2f(f3.y);
    }
  } else {  // chunked wave path (degree > 64 — rare)
    float lm = -INFINITY;
    for (int t = lane; t < n; t += 64) {
      int sv = adj_src[beg + t];
      float v = el[sv] + er_d;
      v = v > 0.f ? v : 0.2f * v;
      lm = fmaxf(lm, v);
    }
#pragma unroll
    for (int off = 32; off; off >>= 1) lm = fmaxf(lm, __shfl_xor(lm, off));
    float ls = 0.f;
    for (int t = lane; t < n; t += 64) {
      int sv = adj_src[beg + t];
      float v = el[sv] + er_d;
      v = v > 0.f ? v : 0.2f * v;
      ls += expf(v - lm);
    }
#pragma unroll
    for (int off = 32; off; off >>= 1) ls += __shfl_xor(ls, off);
    for (int base = 0; base < n; base += 64) {
      int t = base + lane;
      int sv = 0; float wt = 0.f;
      if (t < n) {
        sv = adj_src[beg + t];
        float v = el[sv] + er_d;
        v = v > 0.f ? v : 0.2f * v;
        wt = expf(v - lm) / ls;
      }
      int cnt = min(64, n - base);
      for (int j = 0; j < cnt; ++j) {
        int s0 = __shfl(sv, j);
        float w0 = __shfl(wt, j);
        ushort2 f0 = *(const ushort2*)&F[(size_t)s0 * 128 + c0];
        acc.x += w0 * b2f(f0.x);
        acc.y += w0 * b2f(f0.y);
      }
    }
  }
  float2 o;
  o.x = fmaxf(acc.x + bv.x, 0.f);
  o.y = fmaxf(acc.y + bv.y, 0.f);
  *(float2*)&outX[(size_t)d * 128 + c0] = o;
}

// ---------------- atomic-path edge kernels (outer graph + fallback) ----------------
static __device__ __forceinline__ void atomicMaxF(float* addr, float v) {
  int iv = __float_as_int(v);
  if (iv >= 0) atomicMax((int*)addr, iv);
  else atomicMin((unsigned int*)addr, (unsigned int)iv);
}

static __device__ __forceinline__ float edge_score(const float* el, const float* er,
                                                   int sv, int dv) {
  float v = el[sv] + er[dv];
  return v > 0.f ? v : 0.2f * v;
}

__global__ void edge_max_kernel(const float* __restrict__ el,
                                const float* __restrict__ er,
                                const int* __restrict__ src,
                                const int* __restrict__ dst,
                                float* __restrict__ m, int nE) {
  int e = blockIdx.x * 256 + threadIdx.x;
  if (e >= nE) return;
  atomicMaxF(&m[dst[e]], edge_score(el, er, src[e], dst[e]));
}

__global__ void edge_expsum_kernel(const float* __restrict__ el,
                                   const float* __restrict__ er,
                                   const float* __restrict__ m,
                                   const int* __restrict__ src,
                                   const int* __restrict__ dst,
                                   float* __restrict__ s, int nE) {
  int e = blockIdx.x * 256 + threadIdx.x;
  if (e >= nE) return;
  int d = dst[e];
  atomicAdd(&s[d], expf(edge_score(el, er, src[e], d) - m[d]));
}

__global__ __launch_bounds__(128) void edge_aggregate_kernel(
    const float* __restrict__ f, const float* __restrict__ el,
    const float* __restrict__ er, const float* __restrict__ m,
    const float* __restrict__ s, const int* __restrict__ src,
    const int* __restrict__ dst, float* __restrict__ out, int nE) {
  int e = blockIdx.x;
  int d = threadIdx.x;
  int sv = src[e], dv = dst[e];
  float alpha = expf(edge_score(el, er, sv, dv) - m[dv]) / s[dv];
  atomicAdd(&out[(size_t)dv * 128 + d], alpha * f[(size_t)sv * 128 + d]);
}

__global__ void bias_relu_kernel(float* __restrict__ x,
                                 const float* __restrict__ b, int total) {
  int i = blockIdx.x * 256 + threadIdx.x;
  if (i >= total) return;
  x[i] = fmaxf(x[i] + b[i & 127], 0.f);
}

// ---------------- sort pooling ----------------
__global__ __launch_bounds__(64) void row_max_kernel(const float* __restrict__ x,
                                                     float* __restrict__ key) {
  int node = blockIdx.x, lane = threadIdx.x;
  float v = fmaxf(x[(size_t)node * 128 + lane], x[(size_t)node * 128 + 64 + lane]);
#pragma unroll
  for (int off = 32; off; off >>= 1) v = fmaxf(v, __shfl_down(v, off));
  if (lane == 0) key[node] = v;
}

__global__ __launch_bounds__(64) void select_topk_kernel(
    const float* __restrict__ key, int* __restrict__ sel) {
  __shared__ float keys[NPG];
  int g = blockIdx.x, t = threadIdx.x;
  keys[t] = key[(size_t)g * NPG + t];
  __syncthreads();
  float myk = keys[t];
  int rank = 0;
  for (int j = 0; j < NPG; ++j) {
    float kj = keys[j];
    rank += (kj > myk) || (kj == myk && j < t);
  }
  if (rank < KK) sel[g * KK + rank] = t;
}

__global__ __launch_bounds__(128) void sort_rows_kernel(
    const float* __restrict__ x, const int* __restrict__ sel,
    float* __restrict__ xp) {
  __shared__ float v[128];
  int b = blockIdx.x;
  int t = threadIdx.x;
  int g = b >> 3, r = b & 7;
  int node = sel[b];
  v[t] = x[(size_t)(g * NPG + node) * 128 + t];
  __syncthreads();
  for (int k = 2; k <= 128; k <<= 1) {
    for (int j = k >> 1; j > 0; j >>= 1) {
      int ixj = t ^ j;
      if (ixj > t) {
        float a = v[t], bb = v[ixj];
        bool asc = ((t & k) == 0);
        if (asc ? (a > bb) : (a < bb)) { v[t] = bb; v[ixj] = a; }
      }
      __syncthreads();
    }
  }
  xp[(size_t)g * (KK * 128) + r * 128 + t] = v[t];
}

// ---------------- classifier ----------------
__global__ __launch_bounds__(64) void classifier_kernel(
    const float* __restrict__ x, const float* __restrict__ Wc,
    const float* __restrict__ bc, float* __restrict__ out) {
  int g = blockIdx.x, lane = threadIdx.x;
  float v1 = x[(size_t)g * 128 + lane];
  float v2 = x[(size_t)g * 128 + 64 + lane];
  float a0 = v1 * Wc[lane * 2 + 0] + v2 * Wc[(64 + lane) * 2 + 0];
  float a1 = v1 * Wc[lane * 2 + 1] + v2 * Wc[(64 + lane) * 2 + 1];
#pragma unroll
  for (int off = 32; off; off >>= 1) {
    a0 += __shfl_down(a0, off);
    a1 += __shfl_down(a1, off);
  }
  if (lane == 0) {
    out[g * 2 + 0] = a0 + bc[0];
    out[g * 2 + 1] = a1 + bc[1];
  }
}

// ---------------- launcher ----------------
extern "C" void kernel_launch(void* const* d_in, const int* in_sizes, int n_in,
                              void* d_out, int out_size, void* d_ws, size_t ws_size,
                              hipStream_t stream) {
  const size_t BASE_FLOATS = (size_t)NN * DD * 2 + (size_t)NN * 4;  // X,F,el,er,mx,sm
  const size_t CSR_INTS = (size_t)(NN + 1) + NN + EE + 128;          // row_ptr,cursor,adj,part
  if (ws_size < BASE_FLOATS * sizeof(float)) {
    hipMemsetAsync(d_out, 0, (size_t)out_size * sizeof(float), stream);
    return;
  }
  const bool use_csr = ws_size >= BASE_FLOATS * sizeof(float) + CSR_INTS * sizeof(int);

  const int* h      = (const int*)d_in[0];
  const int* g_src  = (const int*)d_in[1];
  const int* g_dst  = (const int*)d_in[2];
  const int* fg_src = (const int*)d_in[3];
  const int* fg_dst = (const int*)d_in[4];
  const float* temb = (const float*)d_in[5];
  const float* W1 = (const float*)d_in[6];
  const float* al1 = (const float*)d_in[7];
  const float* ar1 = (const float*)d_in[8];
  const float* b1 = (const float*)d_in[9];
  const float* W2 = (const float*)d_in[10];
  const float* al2 = (const float*)d_in[11];
  const float* ar2 = (const float*)d_in[12];
  const float* b2 = (const float*)d_in[13];
  const float* W3 = (const float*)d_in[14];
  const float* al3 = (const float*)d_in[15];
  const float* ar3 = (const float*)d_in[16];
  const float* b3 = (const float*)d_in[17];
  const float* Wf = (const float*)d_in[18];
  const float* bfv = (const float*)d_in[19];
  const float* Wl = (const float*)d_in[20];
  const float* bl = (const float*)d_in[21];
  const float* Wl1 = (const float*)d_in[22];
  const float* bl1 = (const float*)d_in[23];
  const float* Wc = (const float*)d_in[24];
  const float* bc = (const float*)d_in[25];
  float* out = (float*)d_out;

  // ---- workspace layout ----
  float* ws = (float*)d_ws;
  float* X  = ws;
  float* F  = X + (size_t)NN * DD;   // used as bf16 (first half) on CSR path
  float* el = F + (size_t)NN * DD;
  float* er = el + NN;
  float* mx = er + NN;
  float* sm = mx + NN;
  int* row_ptr = (int*)(sm + NN);
  int* cursor  = row_ptr + NN + 1;
  int* adj_src = cursor + NN;
  int* part    = adj_src + EE;
  // carved from F once F is dead (after layer-2 aggregation):
  float* xp   = F;
  float* f3   = F + 2097152;
  float* g3   = f3 + (size_t)GG * DD;
  float* t1   = g3 + (size_t)GG * DD;
  float* t2   = t1 + (size_t)GG * DD;
  float* keyb = t2 + (size_t)GG * DD;
  int*   sel  = (int*)(keyb + NN);

  const int totalND = NN * DD;

  if (use_csr) {
    bfu* Fb = (bfu*)F;
    // ---- build CSR of inner graph by dst (reused by both GAT layers) ----
    zero_int_kernel<<<NN / 256, 256, 0, stream>>>(cursor, NN);
    hist_kernel<<<EE / 256, 256, 0, stream>>>(g_dst, cursor, EE);
    scan_block_kernel<<<NN / 1024, 256, 0, stream>>>(cursor, row_ptr, part);
    scan_part_kernel<<<1, 128, 0, stream>>>(part);
    scan_add_kernel<<<(NN + 255) / 256, 256, 0, stream>>>(row_ptr, part, NN, EE);
    zero_int_kernel<<<NN / 256, 256, 0, stream>>>(cursor, NN);
    scatter_kernel<<<EE / 256, 256, 0, stream>>>(g_dst, g_src, row_ptr, cursor, adj_src, EE);

    // layer 1: F(bf16) = relu(temb[h]) @ W1 fused with embed-gather + el/er epilogue
    gemm128_fused<1, 1><<<NN / 64, 256, 0, stream>>>(
        nullptr, temb, h, W1, nullptr, Fb, al1, ar1, el, er, nullptr);
    gat_aggregate_csr_kernel<<<NN / 4, 256, 0, stream>>>(Fb, el, er, row_ptr, adj_src, b1, X);

    // layer 2
    gemm128_fused<0, 1><<<NN / 64, 256, 0, stream>>>(
        X, nullptr, nullptr, W2, nullptr, Fb, al2, ar2, el, er, nullptr);
    gat_aggregate_csr_kernel<<<NN / 4, 256, 0, stream>>>(Fb, el, er, row_ptr, adj_src, b2, X);

    // linear_forward in-place + fused row-max
    gemm128_fused<0, 2><<<NN / 64, 256, 0, stream>>>(
        X, nullptr, nullptr, Wf, bfv, X, nullptr, nullptr, nullptr, nullptr, keyb);
  } else {
    embed_relu_kernel<<<totalND / 256, 256, 0, stream>>>(temb, h, X, totalND);
    auto gat_inner = [&](const float* W, const float* al, const float* ar, const float* bb) {
      gemm_kernel<DD, 8><<<NN / 8, 128, 0, stream>>>(X, W, nullptr, F, 0);
      attn_logits_kernel<<<NN, 64, 0, stream>>>(F, al, ar, el, er);
      init_softmax_kernel<<<(NN + 255) / 256, 256, 0, stream>>>(mx, sm, NN);
      fill_f32_kernel<<<totalND / 256, 256, 0, stream>>>(X, 0.f, totalND);
      edge_max_kernel<<<(EE + 255) / 256, 256, 0, stream>>>(el, er, g_src, g_dst, mx, EE);
      edge_expsum_kernel<<<(EE + 255) / 256, 256, 0, stream>>>(el, er, mx, g_src, g_dst, sm, EE);
      edge_aggregate_kernel<<<EE, 128, 0, stream>>>(F, el, er, mx, sm, g_src, g_dst, X, EE);
      bias_relu_kernel<<<totalND / 256, 256, 0, stream>>>(X, bb, totalND);
    };
    gat_inner(W1, al1, ar1, b1);
    gat_inner(W2, al2, ar2, b2);
    gemm_kernel<DD, 8><<<NN / 8, 128, 0, stream>>>(X, Wf, bfv, X, 1);
    row_max_kernel<<<NN, 64, 0, stream>>>(X, keyb);
  }

  // sort pooling -> xp [G, 1024]
  select_topk_kernel<<<GG, 64, 0, stream>>>(keyb, sel);
  sort_rows_kernel<<<GG * KK, 128, 0, stream>>>(X, sel, xp);

  // outer GAT over fg (atomic path — small)
  gemm1024_kernel<<<GG / 8, 256, 0, stream>>>(xp, W3, f3);
  attn_logits_kernel<<<GG, 64, 0, stream>>>(f3, al3, ar3, el, er);
  init_softmax_kernel<<<(GG + 255) / 256, 256, 0, stream>>>(mx, sm, GG);
  fill_f32_kernel<<<(GG * DD + 255) / 256, 256, 0, stream>>>(g3, 0.f, GG * DD);
  edge_max_kernel<<<(EFN + 255) / 256, 256, 0, stream>>>(el, er, fg_src, fg_dst, mx, EFN);
  edge_expsum_kernel<<<(EFN + 255) / 256, 256, 0, stream>>>(el, er, mx, fg_src, fg_dst, sm, EFN);
  edge_aggregate_kernel<<<EFN, 128, 0, stream>>>(f3, el, er, mx, sm, fg_src, fg_dst, g3, EFN);
  bias_relu_kernel<<<(GG * DD + 255) / 256, 256, 0, stream>>>(g3, b3, GG * DD);

  // t1 = relu(g3 @ Wl + bl); t2 = relu(t1 @ Wl1 + bl1)
  gemm_kernel<DD, 8><<<GG / 8, 128, 0, stream>>>(g3, Wl, bl, t1, 1);
  gemm_kernel<DD, 8><<<GG / 8, 128, 0, stream>>>(t1, Wl1, bl1, t2, 1);

  // classifier -> fp32 out [G,2]
  classifier_kernel<<<GG, 64, 0, stream>>>(t2, Wc, bc, out);
}